// Round 13
// baseline (160.751 us; speedup 1.0000x reference)
//
#include <hip/hip_runtime.h>
#include <hip/hip_bf16.h>

typedef __attribute__((ext_vector_type(8))) short bf16x8;
typedef __attribute__((ext_vector_type(4))) float f32x4;

namespace {
constexpr int kC = 256;
constexpr int kN = 2048;
constexpr int kB = 4;
constexpr int kHeads = 7;
constexpr int kOC = kHeads * 64;     // 448
constexpr int kSplit = 2;
constexpr int kMChunk = kN / kSplit; // 1024
constexpr float kLog2e = 1.44269504f;
}

static __device__ __forceinline__ float bf2f(ushort u) {
    union { unsigned u; float f; } v; v.u = ((unsigned)u) << 16;
    return v.f;
}
// packed f32x2 -> bf16x2 (RNE); lowers to v_cvt_pk_bf16_f32 when available
static __device__ __forceinline__ unsigned pk_bf16(float a, float b) {
    __hip_bfloat162 h = __float22bfloat162_rn(make_float2(a, b));
    union { __hip_bfloat162 h; unsigned u; } v; v.h = h;
    return v.u;
}
static __device__ __forceinline__ ushort4 pack4bf(float a, float b, float c, float d) {
    union { ushort4 s; uint2 u; } v;
    v.u.x = pk_bf16(a, b); v.u.y = pk_bf16(c, d);
    return v.s;
}
static __device__ __forceinline__ float fexp2(float x) {
#if __has_builtin(__builtin_amdgcn_exp2f)
    return __builtin_amdgcn_exp2f(x);
#else
    return exp2f(x);
#endif
}
// async global->LDS DMA, 16 B per lane. lds dest = l + lane*16 (wave-uniform l).
static __device__ __forceinline__ void g2l16(const ushort* g, ushort* l) {
    __builtin_amdgcn_global_load_lds(
        (const __attribute__((address_space(1))) void*)g,
        (__attribute__((address_space(3))) void*)l,
        16, 0, 0);
}

// ---------------- fused prep: weight cast + x transpose (one launch) -------
__global__ __launch_bounds__(256) void prep_kernel(
    const float* __restrict__ x,
    const float* __restrict__ Wq, const float* __restrict__ Wk,
    const float* __restrict__ Wv, const float* __restrict__ Wf,
    ushort* __restrict__ xT,
    ushort* __restrict__ wq, ushort* __restrict__ wk,
    ushort* __restrict__ wv, ushort* __restrict__ wf)
{
    __shared__ float T[64][65];
    const int bid = blockIdx.x;
    const int tid = threadIdx.x;
    if (bid < 512) {
        // ---- transpose+cast: x[b][c][n] fp32 -> xT[b][n][c] bf16 ----
        const int nt = bid & 31, ct = (bid >> 5) & 3, b = bid >> 7;
        const float* xb = x + ((size_t)b * kC + ct * 64) * kN + nt * 64;
#pragma unroll
        for (int p = 0; p < 16; ++p) {
            int idx = p * 256 + tid;
            int cc = idx >> 6, nn = idx & 63;
            T[cc][nn] = xb[(size_t)cc * kN + nn];
        }
        __syncthreads();
        ushort* xTb = xT + ((size_t)b * kN + nt * 64) * kC + ct * 64;
#pragma unroll
        for (int p = 0; p < 4; ++p) {
            int nn = p * 16 + (tid >> 4);
            int c4 = (tid & 15) * 4;
            *(ushort4*)&xTb[(size_t)nn * kC + c4] =
                pack4bf(T[c4 + 0][nn], T[c4 + 1][nn], T[c4 + 2][nn], T[c4 + 3][nn]);
        }
    } else {
        // ---- weight cast fp32 -> bf16 ----
        const int j = bid - 512;            // 0..447
        const int which = j / 112, bx = j % 112;
        const float* src = which == 0 ? Wq : which == 1 ? Wk : which == 2 ? Wv : Wf;
        ushort* dst      = which == 0 ? wq : which == 1 ? wk : which == 2 ? wv : wf;
        int n = (which == 3) ? kC * kOC : kC * kC;
        int i = (bx * 256 + tid) * 4;
        if (i < n) {
            float4 v = *(const float4*)(src + i);
            *(ushort4*)(dst + i) = pack4bf(v.x, v.y, v.z, v.w);
        }
    }
}

// ---------------- QKV projection: 128x128 tile, 512 threads (8 waves) ------
// R27 (kept): (512,2) = 4 waves/SIMD, per-wave work halved, XCD swizzle.
__global__ __launch_bounds__(512, 2) void qkv_kernel(
    const ushort* __restrict__ xT,
    const ushort* __restrict__ Wqb, const ushort* __restrict__ Wkb, const ushort* __restrict__ Wvb,
    const float* __restrict__ sq, const float* __restrict__ bq,
    const float* __restrict__ sk, const float* __restrict__ bk,
    const float* __restrict__ sv, const float* __restrict__ bv,
    ushort* __restrict__ qT, ushort* __restrict__ kT, ushort* __restrict__ vB)
{
    const int j   = blockIdx.x;              // 0..383
    const int lid = (j & 7) * 48 + (j >> 3); // XCD-grouped
    const int nt  = lid & 15;
    const int ot  = (lid >> 4) & 1;
    const int zz  = lid >> 5;                // 0..11
    const int b   = zz / 3;
    const int mat = zz % 3;
    const ushort* Wb = mat == 0 ? Wqb : mat == 1 ? Wkb : Wvb;
    const float* sm = mat == 0 ? sq : mat == 1 ? sk : sv;
    const float* bm = mat == 0 ? bq : mat == 1 ? bk : bv;

    __shared__ __align__(16) ushort lds[4][128 * 64];   // 64 KB

    const int tid = threadIdx.x;
    const int lane = tid & 63, wav = tid >> 6;   // 8 waves
    const int quad = lane >> 4, l16 = lane & 15;
    const int oh = wav >> 2;     // 0/1: rowB 64-row half
    const int nq = wav & 3;      // 0..3: colB 32-row quarter

    const ushort* xTb = xT + ((size_t)b * kN + nt * 128) * kC;
    const ushort* Wt  = Wb + (size_t)(ot * 128) * kC;

    f32x4 acc[4][2];
#pragma unroll
    for (int mt = 0; mt < 4; ++mt)
#pragma unroll
        for (int ntt = 0; ntt < 2; ++ntt)
#pragma unroll
            for (int r = 0; r < 4; ++r) acc[mt][ntt][r] = 0.f;

    const int sa   = lane >> 3;           // dest sub-row within 8-row chunk
    const int sblk = (lane & 7) ^ sa;     // source block (swizzle on source)
    auto dmaK = [&](int k0, int buf) {
#pragma unroll
        for (int p = 0; p < 2; ++p) {
            int row = wav * 16 + p * 8 + sa;
            size_t so = (size_t)row * kC + k0 + sblk * 8;
            int dbase = (wav * 16 + p * 8) * 64;
            g2l16(Wt + so,  &lds[buf][dbase]);
            g2l16(xTb + so, &lds[2 + buf][dbase]);
        }
    };

    dmaK(0, 0);
    __syncthreads();

    for (int kt = 0; kt < 4; ++kt) {
        const int cur = kt & 1;
        const bool more = (kt < 3);
        if (more) dmaK((kt + 1) * 64, cur ^ 1);

        const ushort* rowB = (mat < 2) ? lds[cur] : lds[2 + cur];
        const ushort* colB = (mat < 2) ? lds[2 + cur] : lds[cur];
#pragma unroll
        for (int ks = 0; ks < 2; ++ks) {
            bf16x8 bfr[2];
#pragma unroll
            for (int ntt = 0; ntt < 2; ++ntt) {
                int row = nq * 32 + ntt * 16 + l16;
                bfr[ntt] = *(const bf16x8*)&colB[row * 64 + (((ks * 4 + quad) ^ (row & 7)) * 8)];
            }
#pragma unroll
            for (int mt = 0; mt < 4; ++mt) {
                int row = oh * 64 + mt * 16 + l16;
                bf16x8 af = *(const bf16x8*)&rowB[row * 64 + (((ks * 4 + quad) ^ (row & 7)) * 8)];
#pragma unroll
                for (int ntt = 0; ntt < 2; ++ntt)
                    acc[mt][ntt] = __builtin_amdgcn_mfma_f32_16x16x32_bf16(
                        af, bfr[ntt], acc[mt][ntt], 0, 0, 0);
            }
        }
        __syncthreads();
    }

    // epilogue: 128x128 transpose gather in lds[0..1] (32 KB, contiguous)
    ushort* sT = &lds[0][0];
    const float qs = (mat == 0) ? kLog2e : 1.f;   // bake log2e into q

    if (mat < 2) {
#pragma unroll
        for (int mt = 0; mt < 4; ++mt) {
            float4 sc4 = *(const float4*)&sm[ot * 128 + oh * 64 + mt * 16 + quad * 4];
            float4 bi4 = *(const float4*)&bm[ot * 128 + oh * 64 + mt * 16 + quad * 4];
#pragma unroll
            for (int ntt = 0; ntt < 2; ++ntt) {
                int nrow = nq * 32 + ntt * 16 + l16;
                float v0 = fmaf(acc[mt][ntt][0], sc4.x, bi4.x) * qs;
                float v1 = fmaf(acc[mt][ntt][1], sc4.y, bi4.y) * qs;
                float v2 = fmaf(acc[mt][ntt][2], sc4.z, bi4.z) * qs;
                float v3 = fmaf(acc[mt][ntt][3], sc4.w, bi4.w) * qs;
                int cb = (oh * 8 + mt * 2 + (quad >> 1)) ^ (nrow & 15);
                *(ushort4*)&sT[nrow * 128 + cb * 8 + (quad & 1) * 4] =
                    pack4bf(v0 > 0.f ? v0 : 0.f, v1 > 0.f ? v1 : 0.f,
                            v2 > 0.f ? v2 : 0.f, v3 > 0.f ? v3 : 0.f);
            }
        }
        __syncthreads();
        ushort* out = (mat == 0) ? qT : kT;
#pragma unroll
        for (int p = 0; p < 4; ++p) {
            int idx = p * 512 + tid;
            int row = idx >> 4, blk = idx & 15;   // row = n_local
            int4 d = *(const int4*)&sT[row * 128 + ((blk ^ (row & 15)) * 8)];
            *(int4*)&out[((size_t)b * kN + nt * 128 + row) * kC + ot * 128 + blk * 8] = d;
        }
    } else {
#pragma unroll
        for (int ntt = 0; ntt < 2; ++ntt) {
            int orow = nq * 32 + ntt * 16 + l16;
            float sc = sm[ot * 128 + orow], bi = bm[ot * 128 + orow];
#pragma unroll
            for (int mt = 0; mt < 4; ++mt) {
                float v0 = fmaf(acc[mt][ntt][0], sc, bi);
                float v1 = fmaf(acc[mt][ntt][1], sc, bi);
                float v2 = fmaf(acc[mt][ntt][2], sc, bi);
                float v3 = fmaf(acc[mt][ntt][3], sc, bi);
                int cb = (oh * 8 + mt * 2 + (quad >> 1)) ^ (orow & 15);
                *(ushort4*)&sT[orow * 128 + cb * 8 + (quad & 1) * 4] =
                    pack4bf(v0 > 0.f ? v0 : 0.f, v1 > 0.f ? v1 : 0.f,
                            v2 > 0.f ? v2 : 0.f, v3 > 0.f ? v3 : 0.f);
            }
        }
        __syncthreads();
#pragma unroll
        for (int p = 0; p < 4; ++p) {
            int idx = p * 512 + tid;
            int row = idx >> 4, blk = idx & 15;   // row = o_local
            int4 d = *(const int4*)&sT[row * 128 + ((blk ^ (row & 15)) * 8)];
            *(int4*)&vB[((size_t)b * kC + ot * 128 + row) * kN + nt * 128 + blk * 8] = d;
        }
    }
}

// ---------------- MFMA flash attention: T15 1-tile software pipeline -------
// R29: loop body is SM(t) -> QK(t+1) -> PV(t) over 3 LDS buffers (48 KB).
//   (a) SM(t) consumes sprev (QK'd LAST iter): starts right after the
//       barrier with zero LDS/MFMA dependency (was: ds_read 120cy + 16-MFMA
//       issue before first exp).
//   (b) QK(t+1) MFMAs are independent of SM/regroup VALU -> both pipes
//       co-issue within one wave (was strictly serial).
//   QK(t+1) overwrites sprev in place (dead after SM) -> peak ~16+32+32+16
//   VGPR, safely <=128 for 2 blk/CU; (512,2) so no forced spill (R7 lesson).
//   Rotation safety: dma(t+2)->buf[(t+2)%3]; its last readers (QK(t) at
//   iter t-1, PV(t-1)) finished before barrier(t-1) < issue.  Deferred
//   row-sum reduce (R10-proven).  Geometry = R6-best: kSplit=2, 448 blocks,
//   XCD grouping, permlane P-regroup.
__global__ __launch_bounds__(512, 2) void attn_kernel(
    const ushort* __restrict__ qT, const ushort* __restrict__ kT,
    const ushort* __restrict__ vB,
    ushort* __restrict__ Opart, float* __restrict__ Ls)
{
    // XCD-aware decode: lid = (j%8)*56 + j/8; 56-block groups (one per (b,s))
    const int j   = blockIdx.x;
    const int lid = (j & 7) * 56 + (j >> 3);
    const int nt  = lid & 7;            // 8 Q-tiles of 256 rows
    const int rest = lid >> 3;          // 0..55
    const int h = rest % 7;
    const int z = rest / 7;             // 0..7 = (b,s)
    const int s = z & 1;
    const int b = z >> 1;
    const int n0 = nt * 256;

    const int tid = threadIdx.x;
    const int lane = tid & 63, wav = tid >> 6;    // 8 waves
    const int quad = lane >> 4, l16 = lane & 15;

    __shared__ __align__(16) ushort sKV[3][8192];   // 3 x 16 KB (K + V), 48 KB

    const ushort* qTb = qT + (size_t)b * kN * kC;
    const ushort* kTb = kT + (size_t)b * kN * kC;
    const ushort* vbb = vB + ((size_t)b * kC + h * 32) * kN;

    const int arr   = wav >> 2;          // 0 = K (wav 0-3), 1 = V (wav 4-7)
    const int rbase = (wav & 3) * 16;    // 16 rows per wave

    bf16x8 qf[2][2];
#pragma unroll
    for (int kk = 0; kk < 2; ++kk)
#pragma unroll
        for (int nt2 = 0; nt2 < 2; ++nt2) {
            int ng = n0 + wav * 32 + nt2 * 16 + l16;
            qf[kk][nt2] = *(const bf16x8*)(qTb + (size_t)ng * kC + h * 32 + kk * 32 + quad * 8);
        }

    f32x4 oacc[4][2];
#pragma unroll
    for (int wt = 0; wt < 4; ++wt)
#pragma unroll
        for (int nt2 = 0; nt2 < 2; ++nt2)
#pragma unroll
            for (int r = 0; r < 4; ++r) oacc[wt][nt2][r] = 0.f;
    float li[2] = {0.f, 0.f};   // per-lane partials; reduced at epilogue

    const int mstart = s * kMChunk;
    const int NIT = kMChunk / 64;     // 16

    const int sa   = lane >> 3;           // dest sub-row within 8-row chunk
    const int sblk = (lane & 7) ^ sa;     // source block (swizzle on source)
    auto dmaTile = [&](int m0, int buf) {
#pragma unroll
        for (int p = 0; p < 2; ++p) {
            int rl = rbase + p * 8 + sa;
            const ushort* src = (arr == 0)
                ? (kTb + (size_t)(m0 + rl) * kC + h * 32 + sblk * 8)
                : (vbb + (size_t)rl * kN + m0 + sblk * 8);
            g2l16(src, &sKV[buf][arr * 4096 + (rbase + p * 8) * 64]);
        }
    };

    // sprev: S^T scores of the CURRENT tile, computed one iteration ahead.
    f32x4 sprev[4][2];
    auto qk = [&](const ushort* sK) {
#pragma unroll
        for (int mt = 0; mt < 4; ++mt)
#pragma unroll
            for (int nt2 = 0; nt2 < 2; ++nt2)
#pragma unroll
                for (int r = 0; r < 4; ++r) sprev[mt][nt2][r] = 0.f;
        __builtin_amdgcn_s_setprio(1);
#pragma unroll
        for (int kk = 0; kk < 2; ++kk)
#pragma unroll
            for (int mt = 0; mt < 4; ++mt) {
                int row = mt * 16 + l16;
                bf16x8 af = *(const bf16x8*)&sK[row * 64 + (((kk * 4 + quad) ^ (row & 7)) * 8)];
#pragma unroll
                for (int nt2 = 0; nt2 < 2; ++nt2)
                    sprev[mt][nt2] = __builtin_amdgcn_mfma_f32_16x16x32_bf16(
                        af, qf[kk][nt2], sprev[mt][nt2], 0, 0, 0);
            }
        __builtin_amdgcn_s_setprio(0);
    };

    // prologue: tile0 staged+QK'd; tile1 staged
    dmaTile(mstart, 0);
    __syncthreads();
    dmaTile(mstart + 64, 1);
    qk(&sKV[0][0]);
    __syncthreads();

    for (int it = 0; it < NIT; ++it) {
        const int bc = it % 3;            // current tile buffer (V source)
        const int bn = (it + 1) % 3;      // next tile buffer (K source)
        const int bu = (it + 2) % 3;      // future dma target
        if (it + 2 < NIT) dmaTile(mstart + (it + 2) * 64, bu);

        // SM(it): exp2 + pack from sprev (no memory dependency)
        unsigned d[2][4][2];
#pragma unroll
        for (int nt2 = 0; nt2 < 2; ++nt2) {
            float sum = 0.f;
#pragma unroll
            for (int mt = 0; mt < 4; ++mt) {
                float p0 = fexp2(sprev[mt][nt2][0]);
                float p1 = fexp2(sprev[mt][nt2][1]);
                float p2 = fexp2(sprev[mt][nt2][2]);
                float p3 = fexp2(sprev[mt][nt2][3]);
                sum += (p0 + p1) + (p2 + p3);
                d[nt2][mt][0] = pk_bf16(p0, p1);
                d[nt2][mt][1] = pk_bf16(p2, p3);
            }
            li[nt2] += sum;
        }

        // QK(it+1): independent MFMAs; overwrites sprev (dead after SM)
        if (it + 1 < NIT) qk(&sKV[bn][0]);

        // PV(it): regroup d via permlane cascade, MFMA with V of tile it
        const ushort* sV = &sKV[bc][4096];
#pragma unroll
        for (int ks = 0; ks < 2; ++ks) {
            bf16x8 pf[2];
#pragma unroll
            for (int nt2 = 0; nt2 < 2; ++nt2) {
                union { unsigned w[4]; bf16x8 v8; } pu;
#if __has_builtin(__builtin_amdgcn_permlane32_swap) && __has_builtin(__builtin_amdgcn_permlane16_swap)
#pragma unroll
                for (int rd = 0; rd < 2; ++rd) {
                    unsigned a = d[nt2][2 * ks][rd], bb = d[nt2][2 * ks + 1][rd];
                    auto r32 = __builtin_amdgcn_permlane32_swap(a, bb, false, false);
                    auto r16 = __builtin_amdgcn_permlane16_swap(r32[0], r32[1], false, false);
                    pu.w[rd]     = r16[0];
                    pu.w[2 + rd] = r16[1];
                }
#else
                const int gx = ((lane & 16) << 1) + l16;
                const int gy = gx + 16;
                const bool lo = (lane < 32);
#pragma unroll
                for (int rd = 0; rd < 2; ++rd) {
                    unsigned u = d[nt2][2 * ks][rd], v = d[nt2][2 * ks + 1][rd];
                    unsigned xu = (unsigned)__shfl((int)u, gx);
                    unsigned xv = (unsigned)__shfl((int)v, gx);
                    unsigned yu = (unsigned)__shfl((int)u, gy);
                    unsigned yv = (unsigned)__shfl((int)v, gy);
                    pu.w[rd]     = lo ? xu : xv;
                    pu.w[2 + rd] = lo ? yu : yv;
                }
#endif
                pf[nt2] = pu.v8;
            }
            __builtin_amdgcn_s_setprio(1);
#pragma unroll
            for (int wt = 0; wt < 4; ++wt) {
                int wr = wt * 16 + l16;
                bf16x8 vf = *(const bf16x8*)&sV[wr * 64 + (((ks * 4 + quad) ^ (wr & 7)) * 8)];
#pragma unroll
                for (int nt2 = 0; nt2 < 2; ++nt2)
                    oacc[wt][nt2] = __builtin_amdgcn_mfma_f32_16x16x32_bf16(
                        vf, pf[nt2], oacc[wt][nt2], 0, 0, 0);
            }
            __builtin_amdgcn_s_setprio(0);
        }

        __syncthreads();   // drains dma(it+2) + all LDS reads of this iter
    }

    // ---- epilogue: reduce row-sums, stats, LDS-transpose O, store ---------
#pragma unroll
    for (int nt2 = 0; nt2 < 2; ++nt2) {
        li[nt2] += __shfl_xor(li[nt2], 16);
        li[nt2] += __shfl_xor(li[nt2], 32);
    }
#pragma unroll
    for (int nt2 = 0; nt2 < 2; ++nt2) {
        if (quad == 0) {
            int n = n0 + wav * 32 + nt2 * 16 + l16;
            size_t si = ((size_t)(s * kB + b) * kHeads + h) * kN + n;
            Ls[si] = li[nt2];
        }
    }
    ushort* sT = &sKV[0][0];    // 32 KB spans sKV[0..1]; all reads drained
#pragma unroll
    for (int wt = 0; wt < 4; ++wt)
#pragma unroll
        for (int nt2 = 0; nt2 < 2; ++nt2) {
            float inv = 1.f / li[nt2];
            int nrow = wav * 32 + nt2 * 16 + l16;   // 0..255
            int cb = (wt * 2 + (quad >> 1)) ^ (nrow & 7);
            *(ushort4*)&sT[nrow * 64 + cb * 8 + (quad & 1) * 4] =
                pack4bf(oacc[wt][nt2][0] * inv, oacc[wt][nt2][1] * inv,
                        oacc[wt][nt2][2] * inv, oacc[wt][nt2][3] * inv);
        }
    __syncthreads();
    int rsub = tid >> 3, blk = tid & 7;   // rsub 0..63
#pragma unroll
    for (int p = 0; p < 4; ++p) {
        int row = p * 64 + rsub;   // n_local 0..255
        int4 dd = *(const int4*)&sT[row * 64 + ((blk ^ (row & 7)) * 8)];
        *(int4*)&Opart[((size_t)s * kB * kN + (size_t)b * kN + n0 + row) * kOC
                       + h * 64 + blk * 8] = dd;
    }
}

// ---------------- final projection, fused split-combine, dbuf 1-barrier ----
__global__ __launch_bounds__(256, 4) void proj_kernel(
    const ushort* __restrict__ Opart, const float* __restrict__ Ls,
    const ushort* __restrict__ Wfb,
    const float* __restrict__ bf_, const float* __restrict__ sf,
    const float* __restrict__ bff, float* __restrict__ out)
{
    const int nt = blockIdx.x;
    const int ot = blockIdx.y;
    const int b  = blockIdx.z;
    __shared__ __align__(16) ushort sA[2][64 * 64];
    __shared__ __align__(16) ushort sB[2][64 * 64];
    const int tid = threadIdx.x;
    const int lane = tid & 63, wav = tid >> 6;   // wav = o 16-slice
    const int quad = lane >> 4, l16 = lane & 15;

    const ushort* Wt  = Wfb + (size_t)(ot * 64) * kOC;
    const ushort* Op1 = Opart;
    const ushort* Op2 = Opart + (size_t)kB * kN * kOC;
    const size_t soff = (size_t)kB * kHeads * kN;

    f32x4 acc[4];
#pragma unroll
    for (int ntt = 0; ntt < 4; ++ntt)
#pragma unroll
        for (int r = 0; r < 4; ++r) acc[ntt][r] = 0.f;

    int4 areg[2], b1reg[2], b2reg[2];
    float w1a[2], w2a[2];

    auto prefetch = [&](int kt) {
        int k0 = kt * 64;
#pragma unroll
        for (int p = 0; p < 2; ++p) {
            int idx = p * 256 + tid, row = idx >> 3, blk = idx & 7;
            areg[p] = *(const int4*)(Wt + (size_t)row * kOC + k0 + blk * 8);
            int n = nt * 64 + row;
            size_t bo = ((size_t)b * kN + n) * kOC + k0 + blk * 8;
            b1reg[p] = *(const int4*)(Op1 + bo);
            b2reg[p] = *(const int4*)(Op2 + bo);
            size_t si = ((size_t)b * kHeads + kt) * kN + n;
            float l1 = Ls[si], l2 = Ls[si + soff];
            float inv = 1.f / (l1 + l2);
            w1a[p] = l1 * inv; w2a[p] = l2 * inv;
        }
    };
    auto stage = [&](int buf) {
#pragma unroll
        for (int p = 0; p < 2; ++p) {
            int idx = p * 256 + tid, row = idx >> 3, blk = idx & 7;
            *(int4*)&sA[buf][row * 64 + ((blk ^ (row & 7)) * 8)] = areg[p];
            union { int4 v; ushort u[8]; } a, c;
            a.v = b1reg[p]; c.v = b2reg[p];
            float rr[8];
#pragma unroll
            for (int jj = 0; jj < 8; ++jj)
                rr[jj] = bf2f(a.u[jj]) * w1a[p] + bf2f(c.u[jj]) * w2a[p];
            int4 o;
            o.x = (int)pk_bf16(rr[0], rr[1]);
            o.y = (int)pk_bf16(rr[2], rr[3]);
            o.z = (int)pk_bf16(rr[4], rr[5]);
            o.w = (int)pk_bf16(rr[6], rr[7]);
            *(int4*)&sB[buf][row * 64 + ((blk ^ (row & 7)) * 8)] = o;
        }
    };

    prefetch(0);
    stage(0);
    __syncthreads();

    for (int kt = 0; kt < 7; ++kt) {
        const int cur = kt & 1;
        const bool more = (kt < 6);
        if (more) prefetch(kt + 1);
#pragma unroll
        for (int ks = 0; ks < 2; ++ks) {
            int arow = wav * 16 + l16;
            bf16x8 af = *(const bf16x8*)&sA[cur][arow * 64 + (((ks * 4 + quad) ^ (arow & 7)) * 8)];
#pragma unroll
            for (int ntt = 0; ntt < 4; ++ntt) {
                int brow = ntt * 16 + l16;
                bf16x8 bfr = *(const bf16x8*)&sB[cur][brow * 64 + (((ks * 4 + quad) ^ (brow & 7)) * 8)];
                acc[ntt] = __builtin_amdgcn_mfma_f32_16x16x32_bf16(af, bfr, acc[ntt], 0, 0, 0);
            }
        }
        if (more) stage(cur ^ 1);
        __syncthreads();
    }
#pragma unroll
    for (int r = 0; r < 4; ++r) {
        int o = ot * 64 + wav * 16 + quad * 4 + r;
        float bfv = bf_[o], sfv = sf[o], bffv = bff[o];
#pragma unroll
        for (int ntt = 0; ntt < 4; ++ntt) {
            int n = nt * 64 + ntt * 16 + l16;
            float y = fmaf(acc[ntt][r] + bfv, sfv, bffv);
            out[((size_t)b * kC + o) * kN + n] = y > 0.f ? y : 0.f;
        }
    }
}

extern "C" void kernel_launch(void* const* d_in, const int* in_sizes, int n_in,
                              void* d_out, int out_size, void* d_ws, size_t ws_size,
                              hipStream_t stream) {
    const float* x   = (const float*)d_in[0];
    const float* Wq  = (const float*)d_in[1];
    const float* sq  = (const float*)d_in[2];
    const float* bq  = (const float*)d_in[3];
    const float* Wk  = (const float*)d_in[4];
    const float* sk  = (const float*)d_in[5];
    const float* bk  = (const float*)d_in[6];
    const float* Wv  = (const float*)d_in[7];
    const float* sv  = (const float*)d_in[8];
    const float* bv  = (const float*)d_in[9];
    const float* Wf  = (const float*)d_in[10];
    const float* bf_ = (const float*)d_in[11];
    const float* sf  = (const float*)d_in[12];
    const float* bff = (const float*)d_in[13];
    float* out = (float*)d_out;

    char* ws = (char*)d_ws;
    ushort* xT  = (ushort*)(ws);                         // 4,194,304
    ushort* Wqb = (ushort*)(ws + 4194304);               // 131,072
    ushort* Wkb = (ushort*)(ws + 4325376);               // 131,072
    ushort* Wvb = (ushort*)(ws + 4456448);               // 131,072
    ushort* Wfb = (ushort*)(ws + 4587520);               // 229,376
    ushort* qT  = (ushort*)(ws + 4816896);               // 4,194,304
    ushort* kT  = (ushort*)(ws + 9011200);               // 4,194,304
    ushort* vB  = (ushort*)(ws + 13205504);              // 4,194,304
    ushort* Opart = (ushort*)(ws + 17399808);            // 14,680,064
    float*  Ls  = (float*)(ws + 32079872);               // 458,752

    prep_kernel<<<dim3(960), 256, 0, stream>>>(
        x, Wq, Wk, Wv, Wf, xT, Wqb, Wkb, Wvb, Wfb);
    qkv_kernel<<<dim3(384), 512, 0, stream>>>(
        xT, Wqb, Wkb, Wvb, sq, bq, sk, bk, sv, bv, qT, kT, vB);
    attn_kernel<<<dim3(448), 512, 0, stream>>>(
        qT, kT, vB, Opart, Ls);
    proj_kernel<<<dim3(kN / 64, kC / 64, kB), 256, 0, stream>>>(
        Opart, Ls, Wfb, bf_, sf, bff, out);
}

// Round 14
// 151.219 us; speedup vs baseline: 1.0630x; 1.0630x over previous
//
#include <hip/hip_runtime.h>
#include <hip/hip_bf16.h>

typedef __attribute__((ext_vector_type(8))) short bf16x8;
typedef __attribute__((ext_vector_type(4))) float f32x4;

namespace {
constexpr int kC = 256;
constexpr int kN = 2048;
constexpr int kB = 4;
constexpr int kHeads = 7;
constexpr int kOC = kHeads * 64;     // 448
constexpr float kLog2e = 1.44269504f;
}

static __device__ __forceinline__ float bf2f(ushort u) {
    union { unsigned u; float f; } v; v.u = ((unsigned)u) << 16;
    return v.f;
}
// packed f32x2 -> bf16x2 (RNE); lowers to v_cvt_pk_bf16_f32 when available
static __device__ __forceinline__ unsigned pk_bf16(float a, float b) {
    __hip_bfloat162 h = __float22bfloat162_rn(make_float2(a, b));
    union { __hip_bfloat162 h; unsigned u; } v; v.h = h;
    return v.u;
}
static __device__ __forceinline__ ushort4 pack4bf(float a, float b, float c, float d) {
    union { ushort4 s; uint2 u; } v;
    v.u.x = pk_bf16(a, b); v.u.y = pk_bf16(c, d);
    return v.s;
}
static __device__ __forceinline__ float fexp2(float x) {
#if __has_builtin(__builtin_amdgcn_exp2f)
    return __builtin_amdgcn_exp2f(x);
#else
    return exp2f(x);
#endif
}
// async global->LDS DMA, 16 B per lane. lds dest = l + lane*16 (wave-uniform l).
static __device__ __forceinline__ void g2l16(const ushort* g, ushort* l) {
    __builtin_amdgcn_global_load_lds(
        (const __attribute__((address_space(1))) void*)g,
        (__attribute__((address_space(3))) void*)l,
        16, 0, 0);
}

// ---------------- fused prep: weight cast + x transpose (one launch) -------
__global__ __launch_bounds__(256) void prep_kernel(
    const float* __restrict__ x,
    const float* __restrict__ Wq, const float* __restrict__ Wk,
    const float* __restrict__ Wv, const float* __restrict__ Wf,
    ushort* __restrict__ xT,
    ushort* __restrict__ wq, ushort* __restrict__ wk,
    ushort* __restrict__ wv, ushort* __restrict__ wf)
{
    __shared__ float T[64][65];
    const int bid = blockIdx.x;
    const int tid = threadIdx.x;
    if (bid < 512) {
        // ---- transpose+cast: x[b][c][n] fp32 -> xT[b][n][c] bf16 ----
        const int nt = bid & 31, ct = (bid >> 5) & 3, b = bid >> 7;
        const float* xb = x + ((size_t)b * kC + ct * 64) * kN + nt * 64;
#pragma unroll
        for (int p = 0; p < 16; ++p) {
            int idx = p * 256 + tid;
            int cc = idx >> 6, nn = idx & 63;
            T[cc][nn] = xb[(size_t)cc * kN + nn];
        }
        __syncthreads();
        ushort* xTb = xT + ((size_t)b * kN + nt * 64) * kC + ct * 64;
#pragma unroll
        for (int p = 0; p < 4; ++p) {
            int nn = p * 16 + (tid >> 4);
            int c4 = (tid & 15) * 4;
            *(ushort4*)&xTb[(size_t)nn * kC + c4] =
                pack4bf(T[c4 + 0][nn], T[c4 + 1][nn], T[c4 + 2][nn], T[c4 + 3][nn]);
        }
    } else {
        // ---- weight cast fp32 -> bf16 ----
        const int j = bid - 512;            // 0..447
        const int which = j / 112, bx = j % 112;
        const float* src = which == 0 ? Wq : which == 1 ? Wk : which == 2 ? Wv : Wf;
        ushort* dst      = which == 0 ? wq : which == 1 ? wk : which == 2 ? wv : wf;
        int n = (which == 3) ? kC * kOC : kC * kC;
        int i = (bx * 256 + tid) * 4;
        if (i < n) {
            float4 v = *(const float4*)(src + i);
            *(ushort4*)(dst + i) = pack4bf(v.x, v.y, v.z, v.w);
        }
    }
}

// ---------------- QKV projection: 128x128 tile, 512 threads (8 waves) ------
// R27 (kept): (512,2) = 4 waves/SIMD, per-wave work halved, XCD swizzle.
__global__ __launch_bounds__(512, 2) void qkv_kernel(
    const ushort* __restrict__ xT,
    const ushort* __restrict__ Wqb, const ushort* __restrict__ Wkb, const ushort* __restrict__ Wvb,
    const float* __restrict__ sq, const float* __restrict__ bq,
    const float* __restrict__ sk, const float* __restrict__ bk,
    const float* __restrict__ sv, const float* __restrict__ bv,
    ushort* __restrict__ qT, ushort* __restrict__ kT, ushort* __restrict__ vB)
{
    const int j   = blockIdx.x;              // 0..383
    const int lid = (j & 7) * 48 + (j >> 3); // XCD-grouped
    const int nt  = lid & 15;
    const int ot  = (lid >> 4) & 1;
    const int zz  = lid >> 5;                // 0..11
    const int b   = zz / 3;
    const int mat = zz % 3;
    const ushort* Wb = mat == 0 ? Wqb : mat == 1 ? Wkb : Wvb;
    const float* sm = mat == 0 ? sq : mat == 1 ? sk : sv;
    const float* bm = mat == 0 ? bq : mat == 1 ? bk : bv;

    __shared__ __align__(16) ushort lds[4][128 * 64];   // 64 KB

    const int tid = threadIdx.x;
    const int lane = tid & 63, wav = tid >> 6;   // 8 waves
    const int quad = lane >> 4, l16 = lane & 15;
    const int oh = wav >> 2;     // 0/1: rowB 64-row half
    const int nq = wav & 3;      // 0..3: colB 32-row quarter

    const ushort* xTb = xT + ((size_t)b * kN + nt * 128) * kC;
    const ushort* Wt  = Wb + (size_t)(ot * 128) * kC;

    f32x4 acc[4][2];
#pragma unroll
    for (int mt = 0; mt < 4; ++mt)
#pragma unroll
        for (int ntt = 0; ntt < 2; ++ntt)
#pragma unroll
            for (int r = 0; r < 4; ++r) acc[mt][ntt][r] = 0.f;

    const int sa   = lane >> 3;           // dest sub-row within 8-row chunk
    const int sblk = (lane & 7) ^ sa;     // source block (swizzle on source)
    auto dmaK = [&](int k0, int buf) {
#pragma unroll
        for (int p = 0; p < 2; ++p) {
            int row = wav * 16 + p * 8 + sa;
            size_t so = (size_t)row * kC + k0 + sblk * 8;
            int dbase = (wav * 16 + p * 8) * 64;
            g2l16(Wt + so,  &lds[buf][dbase]);
            g2l16(xTb + so, &lds[2 + buf][dbase]);
        }
    };

    dmaK(0, 0);
    __syncthreads();

    for (int kt = 0; kt < 4; ++kt) {
        const int cur = kt & 1;
        const bool more = (kt < 3);
        if (more) dmaK((kt + 1) * 64, cur ^ 1);

        const ushort* rowB = (mat < 2) ? lds[cur] : lds[2 + cur];
        const ushort* colB = (mat < 2) ? lds[2 + cur] : lds[cur];
#pragma unroll
        for (int ks = 0; ks < 2; ++ks) {
            bf16x8 bfr[2];
#pragma unroll
            for (int ntt = 0; ntt < 2; ++ntt) {
                int row = nq * 32 + ntt * 16 + l16;
                bfr[ntt] = *(const bf16x8*)&colB[row * 64 + (((ks * 4 + quad) ^ (row & 7)) * 8)];
            }
#pragma unroll
            for (int mt = 0; mt < 4; ++mt) {
                int row = oh * 64 + mt * 16 + l16;
                bf16x8 af = *(const bf16x8*)&rowB[row * 64 + (((ks * 4 + quad) ^ (row & 7)) * 8)];
#pragma unroll
                for (int ntt = 0; ntt < 2; ++ntt)
                    acc[mt][ntt] = __builtin_amdgcn_mfma_f32_16x16x32_bf16(
                        af, bfr[ntt], acc[mt][ntt], 0, 0, 0);
            }
        }
        __syncthreads();
    }

    // epilogue: 128x128 transpose gather in lds[0..1] (32 KB, contiguous)
    ushort* sT = &lds[0][0];
    const float qs = (mat == 0) ? kLog2e : 1.f;   // bake log2e into q

    if (mat < 2) {
#pragma unroll
        for (int mt = 0; mt < 4; ++mt) {
            float4 sc4 = *(const float4*)&sm[ot * 128 + oh * 64 + mt * 16 + quad * 4];
            float4 bi4 = *(const float4*)&bm[ot * 128 + oh * 64 + mt * 16 + quad * 4];
#pragma unroll
            for (int ntt = 0; ntt < 2; ++ntt) {
                int nrow = nq * 32 + ntt * 16 + l16;
                float v0 = fmaf(acc[mt][ntt][0], sc4.x, bi4.x) * qs;
                float v1 = fmaf(acc[mt][ntt][1], sc4.y, bi4.y) * qs;
                float v2 = fmaf(acc[mt][ntt][2], sc4.z, bi4.z) * qs;
                float v3 = fmaf(acc[mt][ntt][3], sc4.w, bi4.w) * qs;
                int cb = (oh * 8 + mt * 2 + (quad >> 1)) ^ (nrow & 15);
                *(ushort4*)&sT[nrow * 128 + cb * 8 + (quad & 1) * 4] =
                    pack4bf(v0 > 0.f ? v0 : 0.f, v1 > 0.f ? v1 : 0.f,
                            v2 > 0.f ? v2 : 0.f, v3 > 0.f ? v3 : 0.f);
            }
        }
        __syncthreads();
        ushort* out = (mat == 0) ? qT : kT;
#pragma unroll
        for (int p = 0; p < 4; ++p) {
            int idx = p * 512 + tid;
            int row = idx >> 4, blk = idx & 15;   // row = n_local
            int4 d = *(const int4*)&sT[row * 128 + ((blk ^ (row & 15)) * 8)];
            *(int4*)&out[((size_t)b * kN + nt * 128 + row) * kC + ot * 128 + blk * 8] = d;
        }
    } else {
#pragma unroll
        for (int ntt = 0; ntt < 2; ++ntt) {
            int orow = nq * 32 + ntt * 16 + l16;
            float sc = sm[ot * 128 + orow], bi = bm[ot * 128 + orow];
#pragma unroll
            for (int mt = 0; mt < 4; ++mt) {
                float v0 = fmaf(acc[mt][ntt][0], sc, bi);
                float v1 = fmaf(acc[mt][ntt][1], sc, bi);
                float v2 = fmaf(acc[mt][ntt][2], sc, bi);
                float v3 = fmaf(acc[mt][ntt][3], sc, bi);
                int cb = (oh * 8 + mt * 2 + (quad >> 1)) ^ (orow & 15);
                *(ushort4*)&sT[orow * 128 + cb * 8 + (quad & 1) * 4] =
                    pack4bf(v0 > 0.f ? v0 : 0.f, v1 > 0.f ? v1 : 0.f,
                            v2 > 0.f ? v2 : 0.f, v3 > 0.f ? v3 : 0.f);
            }
        }
        __syncthreads();
#pragma unroll
        for (int p = 0; p < 4; ++p) {
            int idx = p * 512 + tid;
            int row = idx >> 4, blk = idx & 15;   // row = o_local
            int4 d = *(const int4*)&sT[row * 128 + ((blk ^ (row & 15)) * 8)];
            *(int4*)&vB[((size_t)b * kC + ot * 128 + row) * kN + nt * 128 + blk * 8] = d;
        }
    }
}

// ---------------- MFMA flash attention: kSplit=1, Q-tile 256, 8 waves ------
// R26 (kept): single normalized Opart, no Ls. Grid 224 (8 nt x 7 h x 4 b),
// NIT 32, R6's 2-buffer 1-barrier structure, permlane P-regroup, deferred
// quad-reduce. XCD map 224 = 8 x 28. This pairing measured the session's
// best total (151.0us, R11); T15 pipelining (R13: +12us) and kSplit=2
// recombination (R12: +2.6us) both measured worse.
__global__ __launch_bounds__(512, 2) void attn_kernel(
    const ushort* __restrict__ qT, const ushort* __restrict__ kT,
    const ushort* __restrict__ vB,
    ushort* __restrict__ Opart)
{
    const int j   = blockIdx.x;         // 0..223
    const int lid = (j & 7) * 28 + (j >> 3);
    const int b   = lid / 56;
    const int r2  = lid % 56;
    const int h   = r2 % 7;
    const int nt  = r2 / 7;             // 0..7
    const int n0  = nt * 256;

    const int tid = threadIdx.x;
    const int lane = tid & 63, wav = tid >> 6;    // 8 waves
    const int quad = lane >> 4, l16 = lane & 15;

    __shared__ __align__(16) ushort sKV[2][8192];   // 2 x 16 KB (K + V), 32 KB

    const ushort* qTb = qT + (size_t)b * kN * kC;
    const ushort* kTb = kT + (size_t)b * kN * kC;
    const ushort* vbb = vB + ((size_t)b * kC + h * 32) * kN;

    const int arr   = wav >> 2;          // 0 = K (wav 0-3), 1 = V (wav 4-7)
    const int rbase = (wav & 3) * 16;    // 16 rows per wave

    bf16x8 qf[2][2];
#pragma unroll
    for (int kk = 0; kk < 2; ++kk)
#pragma unroll
        for (int nt2 = 0; nt2 < 2; ++nt2) {
            int ng = n0 + wav * 32 + nt2 * 16 + l16;
            qf[kk][nt2] = *(const bf16x8*)(qTb + (size_t)ng * kC + h * 32 + kk * 32 + quad * 8);
        }

    f32x4 oacc[4][2];
#pragma unroll
    for (int wt = 0; wt < 4; ++wt)
#pragma unroll
        for (int nt2 = 0; nt2 < 2; ++nt2)
#pragma unroll
            for (int r = 0; r < 4; ++r) oacc[wt][nt2][r] = 0.f;
    float li[2] = {0.f, 0.f};   // per-lane partial; quad-aggregated at epilogue

    const int NIT = kN / 64;    // 32

    const int sa   = lane >> 3;           // dest sub-row within 8-row chunk
    const int sblk = (lane & 7) ^ sa;     // source block (swizzle on source)
    auto dmaTile = [&](int m0, int buf) {
#pragma unroll
        for (int p = 0; p < 2; ++p) {
            int rl = rbase + p * 8 + sa;
            const ushort* src = (arr == 0)
                ? (kTb + (size_t)(m0 + rl) * kC + h * 32 + sblk * 8)
                : (vbb + (size_t)rl * kN + m0 + sblk * 8);
            g2l16(src, &sKV[buf][arr * 4096 + (rbase + p * 8) * 64]);
        }
    };

    dmaTile(0, 0);
    __syncthreads();

    for (int it = 0; it < NIT; ++it) {
        const int cur = it & 1;
        const bool more = (it + 1 < NIT);
        if (more) dmaTile((it + 1) * 64, cur ^ 1);

        const ushort* sK = &sKV[cur][0];
        const ushort* sV = &sKV[cur][4096];

        // S^T[m][n] = sum_w K[w][m] Q[w][n]  (Q pre-scaled by log2e)
        f32x4 sacc[4][2];
#pragma unroll
        for (int mt = 0; mt < 4; ++mt)
#pragma unroll
            for (int nt2 = 0; nt2 < 2; ++nt2)
#pragma unroll
                for (int r = 0; r < 4; ++r) sacc[mt][nt2][r] = 0.f;
        __builtin_amdgcn_s_setprio(1);
#pragma unroll
        for (int kk = 0; kk < 2; ++kk)
#pragma unroll
            for (int mt = 0; mt < 4; ++mt) {
                int row = mt * 16 + l16;
                bf16x8 af = *(const bf16x8*)&sK[row * 64 + (((kk * 4 + quad) ^ (row & 7)) * 8)];
#pragma unroll
                for (int nt2 = 0; nt2 < 2; ++nt2)
                    sacc[mt][nt2] = __builtin_amdgcn_mfma_f32_16x16x32_bf16(
                        af, qf[kk][nt2], sacc[mt][nt2], 0, 0, 0);
            }
        __builtin_amdgcn_s_setprio(0);

        // softmax numerators: p = exp2(S') directly; keep packed P in regs.
        unsigned d[2][4][2];
#pragma unroll
        for (int nt2 = 0; nt2 < 2; ++nt2) {
            float sum = 0.f;
#pragma unroll
            for (int mt = 0; mt < 4; ++mt) {
                float p0 = fexp2(sacc[mt][nt2][0]);
                float p1 = fexp2(sacc[mt][nt2][1]);
                float p2 = fexp2(sacc[mt][nt2][2]);
                float p3 = fexp2(sacc[mt][nt2][3]);
                sum += (p0 + p1) + (p2 + p3);
                d[nt2][mt][0] = pk_bf16(p0, p1);
                d[nt2][mt][1] = pk_bf16(p2, p3);
            }
            li[nt2] += sum;   // per-lane partial (this lane's m-slice)
        }

        // O[w][n] += sum_m V[w][m] P[m][n]; C->B regroup via permlane cascade
#pragma unroll
        for (int ks = 0; ks < 2; ++ks) {
            bf16x8 pf[2];
#pragma unroll
            for (int nt2 = 0; nt2 < 2; ++nt2) {
                union { unsigned w[4]; bf16x8 v8; } pu;
#if __has_builtin(__builtin_amdgcn_permlane32_swap) && __has_builtin(__builtin_amdgcn_permlane16_swap)
#pragma unroll
                for (int rd = 0; rd < 2; ++rd) {
                    unsigned a = d[nt2][2 * ks][rd], bb = d[nt2][2 * ks + 1][rd];
                    auto r32 = __builtin_amdgcn_permlane32_swap(a, bb, false, false);
                    auto r16 = __builtin_amdgcn_permlane16_swap(r32[0], r32[1], false, false);
                    pu.w[rd]     = r16[0];
                    pu.w[2 + rd] = r16[1];
                }
#else
                const int gx = ((lane & 16) << 1) + l16;
                const int gy = gx + 16;
                const bool lo = (lane < 32);
#pragma unroll
                for (int rd = 0; rd < 2; ++rd) {
                    unsigned u = d[nt2][2 * ks][rd], v = d[nt2][2 * ks + 1][rd];
                    unsigned xu = (unsigned)__shfl((int)u, gx);
                    unsigned xv = (unsigned)__shfl((int)v, gx);
                    unsigned yu = (unsigned)__shfl((int)u, gy);
                    unsigned yv = (unsigned)__shfl((int)v, gy);
                    pu.w[rd]     = lo ? xu : xv;
                    pu.w[2 + rd] = lo ? yu : yv;
                }
#endif
                pf[nt2] = pu.v8;
            }
            __builtin_amdgcn_s_setprio(1);
#pragma unroll
            for (int wt = 0; wt < 4; ++wt) {
                int wr = wt * 16 + l16;
                bf16x8 vf = *(const bf16x8*)&sV[wr * 64 + (((ks * 4 + quad) ^ (wr & 7)) * 8)];
#pragma unroll
                for (int nt2 = 0; nt2 < 2; ++nt2)
                    oacc[wt][nt2] = __builtin_amdgcn_mfma_f32_16x16x32_bf16(
                        vf, pf[nt2], oacc[wt][nt2], 0, 0, 0);
            }
            __builtin_amdgcn_s_setprio(0);
        }

        __syncthreads();   // drains DMA (vmcnt) + K/V LDS ops (lgkm)
    }

    // ---- epilogue: finish row-sums, normalize, LDS-transpose O, store -----
#pragma unroll
    for (int nt2 = 0; nt2 < 2; ++nt2) {
        li[nt2] += __shfl_xor(li[nt2], 16);
        li[nt2] += __shfl_xor(li[nt2], 32);
    }
    ushort* sT = &sKV[0][0];    // 256 rows x 64 ch x 2B = 32 KB (spans both bufs)
#pragma unroll
    for (int wt = 0; wt < 4; ++wt)
#pragma unroll
        for (int nt2 = 0; nt2 < 2; ++nt2) {
            float inv = 1.f / li[nt2];
            int nrow = wav * 32 + nt2 * 16 + l16;   // 0..255
            int cb = (wt * 2 + (quad >> 1)) ^ (nrow & 7);
            *(ushort4*)&sT[nrow * 64 + cb * 8 + (quad & 1) * 4] =
                pack4bf(oacc[wt][nt2][0] * inv, oacc[wt][nt2][1] * inv,
                        oacc[wt][nt2][2] * inv, oacc[wt][nt2][3] * inv);
        }
    __syncthreads();
    int rsub = tid >> 3, blk = tid & 7;   // rsub 0..63
#pragma unroll
    for (int p = 0; p < 4; ++p) {
        int row = p * 64 + rsub;   // n_local 0..255
        int4 dd = *(const int4*)&sT[row * 64 + ((blk ^ (row & 7)) * 8)];
        *(int4*)&Opart[((size_t)b * kN + n0 + row) * kOC + h * 64 + blk * 8] = dd;
    }
}

// ---------------- final projection: pure DMA-GEMM (kSplit=1) ---------------
__global__ __launch_bounds__(256, 4) void proj_kernel(
    const ushort* __restrict__ Opart, const ushort* __restrict__ Wfb,
    const float* __restrict__ bf_, const float* __restrict__ sf,
    const float* __restrict__ bff, float* __restrict__ out)
{
    const int nt = blockIdx.x;   // 32 tiles of 64 n
    const int ot = blockIdx.y;   // 4 tiles of 64 o
    const int b  = blockIdx.z;
    __shared__ __align__(16) ushort sA[2][64 * 64];   // Wf tile   (16 KB)
    __shared__ __align__(16) ushort sB[2][64 * 64];   // Opart tile (16 KB)
    const int tid = threadIdx.x;
    const int lane = tid & 63, wav = tid >> 6;   // 4 waves
    const int quad = lane >> 4, l16 = lane & 15;

    const ushort* Wt = Wfb + (size_t)(ot * 64) * kOC;
    const ushort* Ob = Opart + ((size_t)b * kN + nt * 64) * kOC;

    f32x4 acc[4];
#pragma unroll
    for (int ntt = 0; ntt < 4; ++ntt)
#pragma unroll
        for (int r = 0; r < 4; ++r) acc[ntt][r] = 0.f;

    const int sa   = lane >> 3;           // dest sub-row within 8-row chunk
    const int sblk = (lane & 7) ^ sa;     // source block (swizzle on source)
    auto dmaT = [&](int kt, int buf) {
        int k0 = kt * 64;
#pragma unroll
        for (int p = 0; p < 2; ++p) {
            int row = wav * 16 + p * 8 + sa;
            int dbase = (wav * 16 + p * 8) * 64;
            g2l16(Wt + (size_t)row * kOC + k0 + sblk * 8, &sA[buf][dbase]);
            g2l16(Ob + (size_t)row * kOC + k0 + sblk * 8, &sB[buf][dbase]);
        }
    };

    dmaT(0, 0);
    __syncthreads();

    for (int kt = 0; kt < 7; ++kt) {
        const int cur = kt & 1;
        const bool more = (kt < 6);
        if (more) dmaT(kt + 1, cur ^ 1);
#pragma unroll
        for (int ks = 0; ks < 2; ++ks) {
            int arow = wav * 16 + l16;
            bf16x8 af = *(const bf16x8*)&sA[cur][arow * 64 + (((ks * 4 + quad) ^ (arow & 7)) * 8)];
#pragma unroll
            for (int ntt = 0; ntt < 4; ++ntt) {
                int brow = ntt * 16 + l16;
                bf16x8 bfr = *(const bf16x8*)&sB[cur][brow * 64 + (((ks * 4 + quad) ^ (brow & 7)) * 8)];
                acc[ntt] = __builtin_amdgcn_mfma_f32_16x16x32_bf16(af, bfr, acc[ntt], 0, 0, 0);
            }
        }
        __syncthreads();
    }
#pragma unroll
    for (int r = 0; r < 4; ++r) {
        int o = ot * 64 + wav * 16 + quad * 4 + r;
        float bfv = bf_[o], sfv = sf[o], bffv = bff[o];
#pragma unroll
        for (int ntt = 0; ntt < 4; ++ntt) {
            int n = nt * 64 + ntt * 16 + l16;
            float y = fmaf(acc[ntt][r] + bfv, sfv, bffv);
            out[((size_t)b * kC + o) * kN + n] = y > 0.f ? y : 0.f;
        }
    }
}

extern "C" void kernel_launch(void* const* d_in, const int* in_sizes, int n_in,
                              void* d_out, int out_size, void* d_ws, size_t ws_size,
                              hipStream_t stream) {
    const float* x   = (const float*)d_in[0];
    const float* Wq  = (const float*)d_in[1];
    const float* sq  = (const float*)d_in[2];
    const float* bq  = (const float*)d_in[3];
    const float* Wk  = (const float*)d_in[4];
    const float* sk  = (const float*)d_in[5];
    const float* bk  = (const float*)d_in[6];
    const float* Wv  = (const float*)d_in[7];
    const float* sv  = (const float*)d_in[8];
    const float* bv  = (const float*)d_in[9];
    const float* Wf  = (const float*)d_in[10];
    const float* bf_ = (const float*)d_in[11];
    const float* sf  = (const float*)d_in[12];
    const float* bff = (const float*)d_in[13];
    float* out = (float*)d_out;

    char* ws = (char*)d_ws;
    ushort* xT  = (ushort*)(ws);                         // 4,194,304
    ushort* Wqb = (ushort*)(ws + 4194304);               // 131,072
    ushort* Wkb = (ushort*)(ws + 4325376);               // 131,072
    ushort* Wvb = (ushort*)(ws + 4456448);               // 131,072
    ushort* Wfb = (ushort*)(ws + 4587520);               // 229,376
    ushort* qT  = (ushort*)(ws + 4816896);               // 4,194,304
    ushort* kT  = (ushort*)(ws + 9011200);               // 4,194,304
    ushort* vB  = (ushort*)(ws + 13205504);              // 4,194,304
    ushort* Opart = (ushort*)(ws + 17399808);            // 7,340,032 (single)

    prep_kernel<<<dim3(960), 256, 0, stream>>>(
        x, Wq, Wk, Wv, Wf, xT, Wqb, Wkb, Wvb, Wfb);
    qkv_kernel<<<dim3(384), 512, 0, stream>>>(
        xT, Wqb, Wkb, Wvb, sq, bq, sk, bk, sv, bv, qT, kT, vB);
    attn_kernel<<<dim3(224), 512, 0, stream>>>(
        qT, kT, vB, Opart);
    proj_kernel<<<dim3(kN / 64, kC / 64, kB), 256, 0, stream>>>(
        Opart, Wfb, bf_, sf, bff, out);
}

// Round 15
// 149.375 us; speedup vs baseline: 1.0762x; 1.0123x over previous
//
#include <hip/hip_runtime.h>
#include <hip/hip_bf16.h>

typedef __attribute__((ext_vector_type(8))) short bf16x8;
typedef __attribute__((ext_vector_type(4))) float f32x4;

namespace {
constexpr int kC = 256;
constexpr int kN = 2048;
constexpr int kB = 4;
constexpr int kHeads = 7;
constexpr int kOC = kHeads * 64;     // 448
constexpr float kLog2e = 1.44269504f;
}

static __device__ __forceinline__ float bf2f(ushort u) {
    union { unsigned u; float f; } v; v.u = ((unsigned)u) << 16;
    return v.f;
}
// packed f32x2 -> bf16x2 (RNE); lowers to v_cvt_pk_bf16_f32 when available
static __device__ __forceinline__ unsigned pk_bf16(float a, float b) {
    __hip_bfloat162 h = __float22bfloat162_rn(make_float2(a, b));
    union { __hip_bfloat162 h; unsigned u; } v; v.h = h;
    return v.u;
}
static __device__ __forceinline__ ushort4 pack4bf(float a, float b, float c, float d) {
    union { ushort4 s; uint2 u; } v;
    v.u.x = pk_bf16(a, b); v.u.y = pk_bf16(c, d);
    return v.s;
}
static __device__ __forceinline__ float fexp2(float x) {
#if __has_builtin(__builtin_amdgcn_exp2f)
    return __builtin_amdgcn_exp2f(x);
#else
    return exp2f(x);
#endif
}
// async global->LDS DMA, 16 B per lane. lds dest = l + lane*16 (wave-uniform l).
static __device__ __forceinline__ void g2l16(const ushort* g, ushort* l) {
    __builtin_amdgcn_global_load_lds(
        (const __attribute__((address_space(1))) void*)g,
        (__attribute__((address_space(3))) void*)l,
        16, 0, 0);
}

// ---------------- fused prep: weight cast + x transpose (one launch) -------
__global__ __launch_bounds__(256) void prep_kernel(
    const float* __restrict__ x,
    const float* __restrict__ Wq, const float* __restrict__ Wk,
    const float* __restrict__ Wv, const float* __restrict__ Wf,
    ushort* __restrict__ xT,
    ushort* __restrict__ wq, ushort* __restrict__ wk,
    ushort* __restrict__ wv, ushort* __restrict__ wf)
{
    __shared__ float T[64][65];
    const int bid = blockIdx.x;
    const int tid = threadIdx.x;
    if (bid < 512) {
        // ---- transpose+cast: x[b][c][n] fp32 -> xT[b][n][c] bf16 ----
        const int nt = bid & 31, ct = (bid >> 5) & 3, b = bid >> 7;
        const float* xb = x + ((size_t)b * kC + ct * 64) * kN + nt * 64;
#pragma unroll
        for (int p = 0; p < 16; ++p) {
            int idx = p * 256 + tid;
            int cc = idx >> 6, nn = idx & 63;
            T[cc][nn] = xb[(size_t)cc * kN + nn];
        }
        __syncthreads();
        ushort* xTb = xT + ((size_t)b * kN + nt * 64) * kC + ct * 64;
#pragma unroll
        for (int p = 0; p < 4; ++p) {
            int nn = p * 16 + (tid >> 4);
            int c4 = (tid & 15) * 4;
            *(ushort4*)&xTb[(size_t)nn * kC + c4] =
                pack4bf(T[c4 + 0][nn], T[c4 + 1][nn], T[c4 + 2][nn], T[c4 + 3][nn]);
        }
    } else {
        // ---- weight cast fp32 -> bf16 ----
        const int j = bid - 512;            // 0..447
        const int which = j / 112, bx = j % 112;
        const float* src = which == 0 ? Wq : which == 1 ? Wk : which == 2 ? Wv : Wf;
        ushort* dst      = which == 0 ? wq : which == 1 ? wk : which == 2 ? wv : wf;
        int n = (which == 3) ? kC * kOC : kC * kC;
        int i = (bx * 256 + tid) * 4;
        if (i < n) {
            float4 v = *(const float4*)(src + i);
            *(ushort4*)(dst + i) = pack4bf(v.x, v.y, v.z, v.w);
        }
    }
}

// ---------------- QKV projection: 128x128 tile, 512 threads (8 waves) ------
// R27 (kept): (512,2) = 4 waves/SIMD, per-wave work halved, XCD swizzle.
__global__ __launch_bounds__(512, 2) void qkv_kernel(
    const ushort* __restrict__ xT,
    const ushort* __restrict__ Wqb, const ushort* __restrict__ Wkb, const ushort* __restrict__ Wvb,
    const float* __restrict__ sq, const float* __restrict__ bq,
    const float* __restrict__ sk, const float* __restrict__ bk,
    const float* __restrict__ sv, const float* __restrict__ bv,
    ushort* __restrict__ qT, ushort* __restrict__ kT, ushort* __restrict__ vB)
{
    const int j   = blockIdx.x;              // 0..383
    const int lid = (j & 7) * 48 + (j >> 3); // XCD-grouped
    const int nt  = lid & 15;
    const int ot  = (lid >> 4) & 1;
    const int zz  = lid >> 5;                // 0..11
    const int b   = zz / 3;
    const int mat = zz % 3;
    const ushort* Wb = mat == 0 ? Wqb : mat == 1 ? Wkb : Wvb;
    const float* sm = mat == 0 ? sq : mat == 1 ? sk : sv;
    const float* bm = mat == 0 ? bq : mat == 1 ? bk : bv;

    __shared__ __align__(16) ushort lds[4][128 * 64];   // 64 KB

    const int tid = threadIdx.x;
    const int lane = tid & 63, wav = tid >> 6;   // 8 waves
    const int quad = lane >> 4, l16 = lane & 15;
    const int oh = wav >> 2;     // 0/1: rowB 64-row half
    const int nq = wav & 3;      // 0..3: colB 32-row quarter

    const ushort* xTb = xT + ((size_t)b * kN + nt * 128) * kC;
    const ushort* Wt  = Wb + (size_t)(ot * 128) * kC;

    f32x4 acc[4][2];
#pragma unroll
    for (int mt = 0; mt < 4; ++mt)
#pragma unroll
        for (int ntt = 0; ntt < 2; ++ntt)
#pragma unroll
            for (int r = 0; r < 4; ++r) acc[mt][ntt][r] = 0.f;

    const int sa   = lane >> 3;           // dest sub-row within 8-row chunk
    const int sblk = (lane & 7) ^ sa;     // source block (swizzle on source)
    auto dmaK = [&](int k0, int buf) {
#pragma unroll
        for (int p = 0; p < 2; ++p) {
            int row = wav * 16 + p * 8 + sa;
            size_t so = (size_t)row * kC + k0 + sblk * 8;
            int dbase = (wav * 16 + p * 8) * 64;
            g2l16(Wt + so,  &lds[buf][dbase]);
            g2l16(xTb + so, &lds[2 + buf][dbase]);
        }
    };

    dmaK(0, 0);
    __syncthreads();

    for (int kt = 0; kt < 4; ++kt) {
        const int cur = kt & 1;
        const bool more = (kt < 3);
        if (more) dmaK((kt + 1) * 64, cur ^ 1);

        const ushort* rowB = (mat < 2) ? lds[cur] : lds[2 + cur];
        const ushort* colB = (mat < 2) ? lds[2 + cur] : lds[cur];
#pragma unroll
        for (int ks = 0; ks < 2; ++ks) {
            bf16x8 bfr[2];
#pragma unroll
            for (int ntt = 0; ntt < 2; ++ntt) {
                int row = nq * 32 + ntt * 16 + l16;
                bfr[ntt] = *(const bf16x8*)&colB[row * 64 + (((ks * 4 + quad) ^ (row & 7)) * 8)];
            }
#pragma unroll
            for (int mt = 0; mt < 4; ++mt) {
                int row = oh * 64 + mt * 16 + l16;
                bf16x8 af = *(const bf16x8*)&rowB[row * 64 + (((ks * 4 + quad) ^ (row & 7)) * 8)];
#pragma unroll
                for (int ntt = 0; ntt < 2; ++ntt)
                    acc[mt][ntt] = __builtin_amdgcn_mfma_f32_16x16x32_bf16(
                        af, bfr[ntt], acc[mt][ntt], 0, 0, 0);
            }
        }
        __syncthreads();
    }

    // epilogue: 128x128 transpose gather in lds[0..1] (32 KB, contiguous)
    ushort* sT = &lds[0][0];
    const float qs = (mat == 0) ? kLog2e : 1.f;   // bake log2e into q

    if (mat < 2) {
#pragma unroll
        for (int mt = 0; mt < 4; ++mt) {
            float4 sc4 = *(const float4*)&sm[ot * 128 + oh * 64 + mt * 16 + quad * 4];
            float4 bi4 = *(const float4*)&bm[ot * 128 + oh * 64 + mt * 16 + quad * 4];
#pragma unroll
            for (int ntt = 0; ntt < 2; ++ntt) {
                int nrow = nq * 32 + ntt * 16 + l16;
                float v0 = fmaf(acc[mt][ntt][0], sc4.x, bi4.x) * qs;
                float v1 = fmaf(acc[mt][ntt][1], sc4.y, bi4.y) * qs;
                float v2 = fmaf(acc[mt][ntt][2], sc4.z, bi4.z) * qs;
                float v3 = fmaf(acc[mt][ntt][3], sc4.w, bi4.w) * qs;
                int cb = (oh * 8 + mt * 2 + (quad >> 1)) ^ (nrow & 15);
                *(ushort4*)&sT[nrow * 128 + cb * 8 + (quad & 1) * 4] =
                    pack4bf(v0 > 0.f ? v0 : 0.f, v1 > 0.f ? v1 : 0.f,
                            v2 > 0.f ? v2 : 0.f, v3 > 0.f ? v3 : 0.f);
            }
        }
        __syncthreads();
        ushort* out = (mat == 0) ? qT : kT;
#pragma unroll
        for (int p = 0; p < 4; ++p) {
            int idx = p * 512 + tid;
            int row = idx >> 4, blk = idx & 15;   // row = n_local
            int4 d = *(const int4*)&sT[row * 128 + ((blk ^ (row & 15)) * 8)];
            *(int4*)&out[((size_t)b * kN + nt * 128 + row) * kC + ot * 128 + blk * 8] = d;
        }
    } else {
#pragma unroll
        for (int ntt = 0; ntt < 2; ++ntt) {
            int orow = nq * 32 + ntt * 16 + l16;
            float sc = sm[ot * 128 + orow], bi = bm[ot * 128 + orow];
#pragma unroll
            for (int mt = 0; mt < 4; ++mt) {
                float v0 = fmaf(acc[mt][ntt][0], sc, bi);
                float v1 = fmaf(acc[mt][ntt][1], sc, bi);
                float v2 = fmaf(acc[mt][ntt][2], sc, bi);
                float v3 = fmaf(acc[mt][ntt][3], sc, bi);
                int cb = (oh * 8 + mt * 2 + (quad >> 1)) ^ (orow & 15);
                *(ushort4*)&sT[orow * 128 + cb * 8 + (quad & 1) * 4] =
                    pack4bf(v0 > 0.f ? v0 : 0.f, v1 > 0.f ? v1 : 0.f,
                            v2 > 0.f ? v2 : 0.f, v3 > 0.f ? v3 : 0.f);
            }
        }
        __syncthreads();
#pragma unroll
        for (int p = 0; p < 4; ++p) {
            int idx = p * 512 + tid;
            int row = idx >> 4, blk = idx & 15;   // row = o_local
            int4 d = *(const int4*)&sT[row * 128 + ((blk ^ (row & 15)) * 8)];
            *(int4*)&vB[((size_t)b * kC + ot * 128 + row) * kN + nt * 128 + blk * 8] = d;
        }
    }
}

// ---------------- MFMA flash attention: kSplit=1, Q-tile 128, 8 waves ------
// R30: fix GRID underfill. R14 counters: VGPR=60 (allows 8 w/SIMD), LDS
// 32KB (allows 5 blk/CU), yet occupancy 17% -> the 224-block grid is the
// binding limit (224 < 256 CUs: 32 CUs idle, no CU holds 2 blocks).
// Q-tile 256 -> 128 (nt2 axis deleted; each wave owns 16 Q-rows): grid
// 448 = 16 nt x 7 h x 4 b -> ~1.75 blk/CU co-resident = ~14 waves/CU,
// 2x today's latency-hiding in the proven chain-latency-bound regime.
// Per-CU total work identical; per-wave regs halve (~45 VGPR). Staging,
// permlane regroup, deferred row-sum, bijective XCD map all unchanged.
__global__ __launch_bounds__(512, 2) void attn_kernel(
    const ushort* __restrict__ qT, const ushort* __restrict__ kT,
    const ushort* __restrict__ vB,
    ushort* __restrict__ Opart)
{
    const int j   = blockIdx.x;         // 0..447
    const int lid = (j & 7) * 56 + (j >> 3);   // XCD-grouped (448 = 8 x 56)
    const int b   = lid / 112;          // 112 = 16 nt x 7 h per batch
    const int r2  = lid % 112;
    const int h   = r2 % 7;
    const int nt  = r2 / 7;             // 0..15
    const int n0  = nt * 128;

    const int tid = threadIdx.x;
    const int lane = tid & 63, wav = tid >> 6;    // 8 waves
    const int quad = lane >> 4, l16 = lane & 15;

    __shared__ __align__(16) ushort sKV[2][8192];   // 2 x 16 KB (K + V), 32 KB

    const ushort* qTb = qT + (size_t)b * kN * kC;
    const ushort* kTb = kT + (size_t)b * kN * kC;
    const ushort* vbb = vB + ((size_t)b * kC + h * 32) * kN;

    const int arr   = wav >> 2;          // 0 = K (wav 0-3), 1 = V (wav 4-7)
    const int rbase = (wav & 3) * 16;    // 16 rows per wave

    // Q fragment: this wave's 16 rows (n = n0 + wav*16 + l16)
    bf16x8 qf[2];
#pragma unroll
    for (int kk = 0; kk < 2; ++kk) {
        int ng = n0 + wav * 16 + l16;
        qf[kk] = *(const bf16x8*)(qTb + (size_t)ng * kC + h * 32 + kk * 32 + quad * 8);
    }

    f32x4 oacc[4];
#pragma unroll
    for (int wt = 0; wt < 4; ++wt)
#pragma unroll
        for (int r = 0; r < 4; ++r) oacc[wt][r] = 0.f;
    float li = 0.f;   // per-lane partial; quad-aggregated at epilogue

    const int NIT = kN / 64;    // 32

    const int sa   = lane >> 3;           // dest sub-row within 8-row chunk
    const int sblk = (lane & 7) ^ sa;     // source block (swizzle on source)
    auto dmaTile = [&](int m0, int buf) {
#pragma unroll
        for (int p = 0; p < 2; ++p) {
            int rl = rbase + p * 8 + sa;
            const ushort* src = (arr == 0)
                ? (kTb + (size_t)(m0 + rl) * kC + h * 32 + sblk * 8)
                : (vbb + (size_t)rl * kN + m0 + sblk * 8);
            g2l16(src, &sKV[buf][arr * 4096 + (rbase + p * 8) * 64]);
        }
    };

    dmaTile(0, 0);
    __syncthreads();

    for (int it = 0; it < NIT; ++it) {
        const int cur = it & 1;
        const bool more = (it + 1 < NIT);
        if (more) dmaTile((it + 1) * 64, cur ^ 1);

        const ushort* sK = &sKV[cur][0];
        const ushort* sV = &sKV[cur][4096];

        // S^T[m][n] = sum_w K[w][m] Q[w][n]  (Q pre-scaled by log2e)
        f32x4 sacc[4];
#pragma unroll
        for (int mt = 0; mt < 4; ++mt)
#pragma unroll
            for (int r = 0; r < 4; ++r) sacc[mt][r] = 0.f;
        __builtin_amdgcn_s_setprio(1);
#pragma unroll
        for (int kk = 0; kk < 2; ++kk)
#pragma unroll
            for (int mt = 0; mt < 4; ++mt) {
                int row = mt * 16 + l16;
                bf16x8 af = *(const bf16x8*)&sK[row * 64 + (((kk * 4 + quad) ^ (row & 7)) * 8)];
                sacc[mt] = __builtin_amdgcn_mfma_f32_16x16x32_bf16(
                    af, qf[kk], sacc[mt], 0, 0, 0);
            }
        __builtin_amdgcn_s_setprio(0);

        // softmax numerators: p = exp2(S') directly; keep packed P in regs.
        unsigned d[4][2];
        {
            float sum = 0.f;
#pragma unroll
            for (int mt = 0; mt < 4; ++mt) {
                float p0 = fexp2(sacc[mt][0]);
                float p1 = fexp2(sacc[mt][1]);
                float p2 = fexp2(sacc[mt][2]);
                float p3 = fexp2(sacc[mt][3]);
                sum += (p0 + p1) + (p2 + p3);
                d[mt][0] = pk_bf16(p0, p1);
                d[mt][1] = pk_bf16(p2, p3);
            }
            li += sum;   // per-lane partial (this lane's m-slice)
        }

        // O[w][n] += sum_m V[w][m] P[m][n]; C->B regroup via permlane cascade
#pragma unroll
        for (int ks = 0; ks < 2; ++ks) {
            bf16x8 pf;
            {
                union { unsigned w[4]; bf16x8 v8; } pu;
#if __has_builtin(__builtin_amdgcn_permlane32_swap) && __has_builtin(__builtin_amdgcn_permlane16_swap)
#pragma unroll
                for (int rd = 0; rd < 2; ++rd) {
                    unsigned a = d[2 * ks][rd], bb = d[2 * ks + 1][rd];
                    auto r32 = __builtin_amdgcn_permlane32_swap(a, bb, false, false);
                    auto r16 = __builtin_amdgcn_permlane16_swap(r32[0], r32[1], false, false);
                    pu.w[rd]     = r16[0];
                    pu.w[2 + rd] = r16[1];
                }
#else
                const int gx = ((lane & 16) << 1) + l16;
                const int gy = gx + 16;
                const bool lo = (lane < 32);
#pragma unroll
                for (int rd = 0; rd < 2; ++rd) {
                    unsigned u = d[2 * ks][rd], v = d[2 * ks + 1][rd];
                    unsigned xu = (unsigned)__shfl((int)u, gx);
                    unsigned xv = (unsigned)__shfl((int)v, gx);
                    unsigned yu = (unsigned)__shfl((int)u, gy);
                    unsigned yv = (unsigned)__shfl((int)v, gy);
                    pu.w[rd]     = lo ? xu : xv;
                    pu.w[2 + rd] = lo ? yu : yv;
                }
#endif
                pf = pu.v8;
            }
            __builtin_amdgcn_s_setprio(1);
#pragma unroll
            for (int wt = 0; wt < 4; ++wt) {
                int wr = wt * 16 + l16;
                bf16x8 vf = *(const bf16x8*)&sV[wr * 64 + (((ks * 4 + quad) ^ (wr & 7)) * 8)];
                oacc[wt] = __builtin_amdgcn_mfma_f32_16x16x32_bf16(
                    vf, pf, oacc[wt], 0, 0, 0);
            }
            __builtin_amdgcn_s_setprio(0);
        }

        __syncthreads();   // drains DMA (vmcnt) + K/V LDS ops (lgkm)
    }

    // ---- epilogue: finish row-sum, normalize, LDS-transpose O, store ------
    li += __shfl_xor(li, 16);
    li += __shfl_xor(li, 32);
    float inv = 1.f / li;
    ushort* sT = &sKV[0][0];    // 128 rows x 64 ch x 2B = 16 KB (buf 0)
#pragma unroll
    for (int wt = 0; wt < 4; ++wt) {
        int nrow = wav * 16 + l16;   // 0..127
        int cb = (wt * 2 + (quad >> 1)) ^ (nrow & 7);
        *(ushort4*)&sT[nrow * 64 + cb * 8 + (quad & 1) * 4] =
            pack4bf(oacc[wt][0] * inv, oacc[wt][1] * inv,
                    oacc[wt][2] * inv, oacc[wt][3] * inv);
    }
    __syncthreads();
    int rsub = tid >> 3, blk = tid & 7;   // rsub 0..63
#pragma unroll
    for (int p = 0; p < 2; ++p) {
        int row = p * 64 + rsub;   // n_local 0..127
        int4 dd = *(const int4*)&sT[row * 64 + ((blk ^ (row & 7)) * 8)];
        *(int4*)&Opart[((size_t)b * kN + n0 + row) * kOC + h * 64 + blk * 8] = dd;
    }
}

// ---------------- final projection: pure DMA-GEMM (kSplit=1) ---------------
__global__ __launch_bounds__(256, 4) void proj_kernel(
    const ushort* __restrict__ Opart, const ushort* __restrict__ Wfb,
    const float* __restrict__ bf_, const float* __restrict__ sf,
    const float* __restrict__ bff, float* __restrict__ out)
{
    const int nt = blockIdx.x;   // 32 tiles of 64 n
    const int ot = blockIdx.y;   // 4 tiles of 64 o
    const int b  = blockIdx.z;
    __shared__ __align__(16) ushort sA[2][64 * 64];   // Wf tile   (16 KB)
    __shared__ __align__(16) ushort sB[2][64 * 64];   // Opart tile (16 KB)
    const int tid = threadIdx.x;
    const int lane = tid & 63, wav = tid >> 6;   // 4 waves
    const int quad = lane >> 4, l16 = lane & 15;

    const ushort* Wt = Wfb + (size_t)(ot * 64) * kOC;
    const ushort* Ob = Opart + ((size_t)b * kN + nt * 64) * kOC;

    f32x4 acc[4];
#pragma unroll
    for (int ntt = 0; ntt < 4; ++ntt)
#pragma unroll
        for (int r = 0; r < 4; ++r) acc[ntt][r] = 0.f;

    const int sa   = lane >> 3;           // dest sub-row within 8-row chunk
    const int sblk = (lane & 7) ^ sa;     // source block (swizzle on source)
    auto dmaT = [&](int kt, int buf) {
        int k0 = kt * 64;
#pragma unroll
        for (int p = 0; p < 2; ++p) {
            int row = wav * 16 + p * 8 + sa;
            int dbase = (wav * 16 + p * 8) * 64;
            g2l16(Wt + (size_t)row * kOC + k0 + sblk * 8, &sA[buf][dbase]);
            g2l16(Ob + (size_t)row * kOC + k0 + sblk * 8, &sB[buf][dbase]);
        }
    };

    dmaT(0, 0);
    __syncthreads();

    for (int kt = 0; kt < 7; ++kt) {
        const int cur = kt & 1;
        const bool more = (kt < 6);
        if (more) dmaT(kt + 1, cur ^ 1);
#pragma unroll
        for (int ks = 0; ks < 2; ++ks) {
            int arow = wav * 16 + l16;
            bf16x8 af = *(const bf16x8*)&sA[cur][arow * 64 + (((ks * 4 + quad) ^ (arow & 7)) * 8)];
#pragma unroll
            for (int ntt = 0; ntt < 4; ++ntt) {
                int brow = ntt * 16 + l16;
                bf16x8 bfr = *(const bf16x8*)&sB[cur][brow * 64 + (((ks * 4 + quad) ^ (brow & 7)) * 8)];
                acc[ntt] = __builtin_amdgcn_mfma_f32_16x16x32_bf16(af, bfr, acc[ntt], 0, 0, 0);
            }
        }
        __syncthreads();
    }
#pragma unroll
    for (int r = 0; r < 4; ++r) {
        int o = ot * 64 + wav * 16 + quad * 4 + r;
        float bfv = bf_[o], sfv = sf[o], bffv = bff[o];
#pragma unroll
        for (int ntt = 0; ntt < 4; ++ntt) {
            int n = nt * 64 + ntt * 16 + l16;
            float y = fmaf(acc[ntt][r] + bfv, sfv, bffv);
            out[((size_t)b * kC + o) * kN + n] = y > 0.f ? y : 0.f;
        }
    }
}

extern "C" void kernel_launch(void* const* d_in, const int* in_sizes, int n_in,
                              void* d_out, int out_size, void* d_ws, size_t ws_size,
                              hipStream_t stream) {
    const float* x   = (const float*)d_in[0];
    const float* Wq  = (const float*)d_in[1];
    const float* sq  = (const float*)d_in[2];
    const float* bq  = (const float*)d_in[3];
    const float* Wk  = (const float*)d_in[4];
    const float* sk  = (const float*)d_in[5];
    const float* bk  = (const float*)d_in[6];
    const float* Wv  = (const float*)d_in[7];
    const float* sv  = (const float*)d_in[8];
    const float* bv  = (const float*)d_in[9];
    const float* Wf  = (const float*)d_in[10];
    const float* bf_ = (const float*)d_in[11];
    const float* sf  = (const float*)d_in[12];
    const float* bff = (const float*)d_in[13];
    float* out = (float*)d_out;

    char* ws = (char*)d_ws;
    ushort* xT  = (ushort*)(ws);                         // 4,194,304
    ushort* Wqb = (ushort*)(ws + 4194304);               // 131,072
    ushort* Wkb = (ushort*)(ws + 4325376);               // 131,072
    ushort* Wvb = (ushort*)(ws + 4456448);               // 131,072
    ushort* Wfb = (ushort*)(ws + 4587520);               // 229,376
    ushort* qT  = (ushort*)(ws + 4816896);               // 4,194,304
    ushort* kT  = (ushort*)(ws + 9011200);               // 4,194,304
    ushort* vB  = (ushort*)(ws + 13205504);              // 4,194,304
    ushort* Opart = (ushort*)(ws + 17399808);            // 7,340,032 (single)

    prep_kernel<<<dim3(960), 256, 0, stream>>>(
        x, Wq, Wk, Wv, Wf, xT, Wqb, Wkb, Wvb, Wfb);
    qkv_kernel<<<dim3(384), 512, 0, stream>>>(
        xT, Wqb, Wkb, Wvb, sq, bq, sk, bk, sv, bv, qT, kT, vB);
    attn_kernel<<<dim3(448), 512, 0, stream>>>(
        qT, kT, vB, Opart);
    proj_kernel<<<dim3(kN / 64, kC / 64, kB), 256, 0, stream>>>(
        Opart, Wfb, bf_, sf, bff, out);
}

// Round 16
// 149.103 us; speedup vs baseline: 1.0781x; 1.0018x over previous
//
#include <hip/hip_runtime.h>
#include <hip/hip_bf16.h>

typedef __attribute__((ext_vector_type(8))) short bf16x8;
typedef __attribute__((ext_vector_type(4))) float f32x4;

namespace {
constexpr int kC = 256;
constexpr int kN = 2048;
constexpr int kB = 4;
constexpr int kHeads = 7;
constexpr int kOC = kHeads * 64;     // 448
constexpr float kLog2e = 1.44269504f;
}

static __device__ __forceinline__ float bf2f(ushort u) {
    union { unsigned u; float f; } v; v.u = ((unsigned)u) << 16;
    return v.f;
}
// packed f32x2 -> bf16x2 (RNE); lowers to v_cvt_pk_bf16_f32 when available
static __device__ __forceinline__ unsigned pk_bf16(float a, float b) {
    __hip_bfloat162 h = __float22bfloat162_rn(make_float2(a, b));
    union { __hip_bfloat162 h; unsigned u; } v; v.h = h;
    return v.u;
}
static __device__ __forceinline__ ushort4 pack4bf(float a, float b, float c, float d) {
    union { ushort4 s; uint2 u; } v;
    v.u.x = pk_bf16(a, b); v.u.y = pk_bf16(c, d);
    return v.s;
}
static __device__ __forceinline__ float fexp2(float x) {
#if __has_builtin(__builtin_amdgcn_exp2f)
    return __builtin_amdgcn_exp2f(x);
#else
    return exp2f(x);
#endif
}
// async global->LDS DMA, 16 B per lane. lds dest = l + lane*16 (wave-uniform l).
static __device__ __forceinline__ void g2l16(const ushort* g, ushort* l) {
    __builtin_amdgcn_global_load_lds(
        (const __attribute__((address_space(1))) void*)g,
        (__attribute__((address_space(3))) void*)l,
        16, 0, 0);
}

// ---------------- fused prep: weight cast + x transpose (one launch) -------
__global__ __launch_bounds__(256) void prep_kernel(
    const float* __restrict__ x,
    const float* __restrict__ Wq, const float* __restrict__ Wk,
    const float* __restrict__ Wv, const float* __restrict__ Wf,
    ushort* __restrict__ xT,
    ushort* __restrict__ wq, ushort* __restrict__ wk,
    ushort* __restrict__ wv, ushort* __restrict__ wf)
{
    __shared__ float T[64][65];
    const int bid = blockIdx.x;
    const int tid = threadIdx.x;
    if (bid < 512) {
        // ---- transpose+cast: x[b][c][n] fp32 -> xT[b][n][c] bf16 ----
        const int nt = bid & 31, ct = (bid >> 5) & 3, b = bid >> 7;
        const float* xb = x + ((size_t)b * kC + ct * 64) * kN + nt * 64;
#pragma unroll
        for (int p = 0; p < 16; ++p) {
            int idx = p * 256 + tid;
            int cc = idx >> 6, nn = idx & 63;
            T[cc][nn] = xb[(size_t)cc * kN + nn];
        }
        __syncthreads();
        ushort* xTb = xT + ((size_t)b * kN + nt * 64) * kC + ct * 64;
#pragma unroll
        for (int p = 0; p < 4; ++p) {
            int nn = p * 16 + (tid >> 4);
            int c4 = (tid & 15) * 4;
            *(ushort4*)&xTb[(size_t)nn * kC + c4] =
                pack4bf(T[c4 + 0][nn], T[c4 + 1][nn], T[c4 + 2][nn], T[c4 + 3][nn]);
        }
    } else {
        // ---- weight cast fp32 -> bf16 ----
        const int j = bid - 512;            // 0..447
        const int which = j / 112, bx = j % 112;
        const float* src = which == 0 ? Wq : which == 1 ? Wk : which == 2 ? Wv : Wf;
        ushort* dst      = which == 0 ? wq : which == 1 ? wk : which == 2 ? wv : wf;
        int n = (which == 3) ? kC * kOC : kC * kC;
        int i = (bx * 256 + tid) * 4;
        if (i < n) {
            float4 v = *(const float4*)(src + i);
            *(ushort4*)(dst + i) = pack4bf(v.x, v.y, v.z, v.w);
        }
    }
}

// ---------------- QKV projection: 128x128 tile, 512 threads (8 waves) ------
// R27 (kept): (512,2) = 4 waves/SIMD, per-wave work halved, XCD swizzle.
__global__ __launch_bounds__(512, 2) void qkv_kernel(
    const ushort* __restrict__ xT,
    const ushort* __restrict__ Wqb, const ushort* __restrict__ Wkb, const ushort* __restrict__ Wvb,
    const float* __restrict__ sq, const float* __restrict__ bq,
    const float* __restrict__ sk, const float* __restrict__ bk,
    const float* __restrict__ sv, const float* __restrict__ bv,
    ushort* __restrict__ qT, ushort* __restrict__ kT, ushort* __restrict__ vB)
{
    const int j   = blockIdx.x;              // 0..383
    const int lid = (j & 7) * 48 + (j >> 3); // XCD-grouped
    const int nt  = lid & 15;
    const int ot  = (lid >> 4) & 1;
    const int zz  = lid >> 5;                // 0..11
    const int b   = zz / 3;
    const int mat = zz % 3;
    const ushort* Wb = mat == 0 ? Wqb : mat == 1 ? Wkb : Wvb;
    const float* sm = mat == 0 ? sq : mat == 1 ? sk : sv;
    const float* bm = mat == 0 ? bq : mat == 1 ? bk : bv;

    __shared__ __align__(16) ushort lds[4][128 * 64];   // 64 KB

    const int tid = threadIdx.x;
    const int lane = tid & 63, wav = tid >> 6;   // 8 waves
    const int quad = lane >> 4, l16 = lane & 15;
    const int oh = wav >> 2;     // 0/1: rowB 64-row half
    const int nq = wav & 3;      // 0..3: colB 32-row quarter

    const ushort* xTb = xT + ((size_t)b * kN + nt * 128) * kC;
    const ushort* Wt  = Wb + (size_t)(ot * 128) * kC;

    f32x4 acc[4][2];
#pragma unroll
    for (int mt = 0; mt < 4; ++mt)
#pragma unroll
        for (int ntt = 0; ntt < 2; ++ntt)
#pragma unroll
            for (int r = 0; r < 4; ++r) acc[mt][ntt][r] = 0.f;

    const int sa   = lane >> 3;           // dest sub-row within 8-row chunk
    const int sblk = (lane & 7) ^ sa;     // source block (swizzle on source)
    auto dmaK = [&](int k0, int buf) {
#pragma unroll
        for (int p = 0; p < 2; ++p) {
            int row = wav * 16 + p * 8 + sa;
            size_t so = (size_t)row * kC + k0 + sblk * 8;
            int dbase = (wav * 16 + p * 8) * 64;
            g2l16(Wt + so,  &lds[buf][dbase]);
            g2l16(xTb + so, &lds[2 + buf][dbase]);
        }
    };

    dmaK(0, 0);
    __syncthreads();

    for (int kt = 0; kt < 4; ++kt) {
        const int cur = kt & 1;
        const bool more = (kt < 3);
        if (more) dmaK((kt + 1) * 64, cur ^ 1);

        const ushort* rowB = (mat < 2) ? lds[cur] : lds[2 + cur];
        const ushort* colB = (mat < 2) ? lds[2 + cur] : lds[cur];
#pragma unroll
        for (int ks = 0; ks < 2; ++ks) {
            bf16x8 bfr[2];
#pragma unroll
            for (int ntt = 0; ntt < 2; ++ntt) {
                int row = nq * 32 + ntt * 16 + l16;
                bfr[ntt] = *(const bf16x8*)&colB[row * 64 + (((ks * 4 + quad) ^ (row & 7)) * 8)];
            }
#pragma unroll
            for (int mt = 0; mt < 4; ++mt) {
                int row = oh * 64 + mt * 16 + l16;
                bf16x8 af = *(const bf16x8*)&rowB[row * 64 + (((ks * 4 + quad) ^ (row & 7)) * 8)];
#pragma unroll
                for (int ntt = 0; ntt < 2; ++ntt)
                    acc[mt][ntt] = __builtin_amdgcn_mfma_f32_16x16x32_bf16(
                        af, bfr[ntt], acc[mt][ntt], 0, 0, 0);
            }
        }
        __syncthreads();
    }

    // epilogue: 128x128 transpose gather in lds[0..1] (32 KB, contiguous)
    ushort* sT = &lds[0][0];
    const float qs = (mat == 0) ? kLog2e : 1.f;   // bake log2e into q

    if (mat < 2) {
#pragma unroll
        for (int mt = 0; mt < 4; ++mt) {
            float4 sc4 = *(const float4*)&sm[ot * 128 + oh * 64 + mt * 16 + quad * 4];
            float4 bi4 = *(const float4*)&bm[ot * 128 + oh * 64 + mt * 16 + quad * 4];
#pragma unroll
            for (int ntt = 0; ntt < 2; ++ntt) {
                int nrow = nq * 32 + ntt * 16 + l16;
                float v0 = fmaf(acc[mt][ntt][0], sc4.x, bi4.x) * qs;
                float v1 = fmaf(acc[mt][ntt][1], sc4.y, bi4.y) * qs;
                float v2 = fmaf(acc[mt][ntt][2], sc4.z, bi4.z) * qs;
                float v3 = fmaf(acc[mt][ntt][3], sc4.w, bi4.w) * qs;
                int cb = (oh * 8 + mt * 2 + (quad >> 1)) ^ (nrow & 15);
                *(ushort4*)&sT[nrow * 128 + cb * 8 + (quad & 1) * 4] =
                    pack4bf(v0 > 0.f ? v0 : 0.f, v1 > 0.f ? v1 : 0.f,
                            v2 > 0.f ? v2 : 0.f, v3 > 0.f ? v3 : 0.f);
            }
        }
        __syncthreads();
        ushort* out = (mat == 0) ? qT : kT;
#pragma unroll
        for (int p = 0; p < 4; ++p) {
            int idx = p * 512 + tid;
            int row = idx >> 4, blk = idx & 15;   // row = n_local
            int4 d = *(const int4*)&sT[row * 128 + ((blk ^ (row & 15)) * 8)];
            *(int4*)&out[((size_t)b * kN + nt * 128 + row) * kC + ot * 128 + blk * 8] = d;
        }
    } else {
#pragma unroll
        for (int ntt = 0; ntt < 2; ++ntt) {
            int orow = nq * 32 + ntt * 16 + l16;
            float sc = sm[ot * 128 + orow], bi = bm[ot * 128 + orow];
#pragma unroll
            for (int mt = 0; mt < 4; ++mt) {
                float v0 = fmaf(acc[mt][ntt][0], sc, bi);
                float v1 = fmaf(acc[mt][ntt][1], sc, bi);
                float v2 = fmaf(acc[mt][ntt][2], sc, bi);
                float v3 = fmaf(acc[mt][ntt][3], sc, bi);
                int cb = (oh * 8 + mt * 2 + (quad >> 1)) ^ (orow & 15);
                *(ushort4*)&sT[orow * 128 + cb * 8 + (quad & 1) * 4] =
                    pack4bf(v0 > 0.f ? v0 : 0.f, v1 > 0.f ? v1 : 0.f,
                            v2 > 0.f ? v2 : 0.f, v3 > 0.f ? v3 : 0.f);
            }
        }
        __syncthreads();
#pragma unroll
        for (int p = 0; p < 4; ++p) {
            int idx = p * 512 + tid;
            int row = idx >> 4, blk = idx & 15;   // row = o_local
            int4 d = *(const int4*)&sT[row * 128 + ((blk ^ (row & 15)) * 8)];
            *(int4*)&vB[((size_t)b * kC + ot * 128 + row) * kN + nt * 128 + blk * 8] = d;
        }
    }
}

// ---------------- MFMA flash attention: kSplit=1, Q-tile 128, 8 waves ------
// R30/R31 (final): grid 448 = 16 nt x 7 h x 4 b at Q-tile 128 (each wave
// owns 16 Q-rows); ~1.75 blk/CU co-resident, VGPR 40, LDS 32KB. Measured
// best total (149.4us, R15); this round is a byte-identical reproduction.
// Session falsification record: occupancy 7->14 waves/CU = -1us (chain-
// bound, not wave-bound); KVBLK-128, counted-vmcnt, T15 pipeline, kSplit
// variants all neutral-to-worse. Remaining headroom would need a 32x32-
// MFMA rewrite (4x FLOP/LDS-byte) of the attention core.
__global__ __launch_bounds__(512, 2) void attn_kernel(
    const ushort* __restrict__ qT, const ushort* __restrict__ kT,
    const ushort* __restrict__ vB,
    ushort* __restrict__ Opart)
{
    const int j   = blockIdx.x;         // 0..447
    const int lid = (j & 7) * 56 + (j >> 3);   // XCD-grouped (448 = 8 x 56)
    const int b   = lid / 112;          // 112 = 16 nt x 7 h per batch
    const int r2  = lid % 112;
    const int h   = r2 % 7;
    const int nt  = r2 / 7;             // 0..15
    const int n0  = nt * 128;

    const int tid = threadIdx.x;
    const int lane = tid & 63, wav = tid >> 6;    // 8 waves
    const int quad = lane >> 4, l16 = lane & 15;

    __shared__ __align__(16) ushort sKV[2][8192];   // 2 x 16 KB (K + V), 32 KB

    const ushort* qTb = qT + (size_t)b * kN * kC;
    const ushort* kTb = kT + (size_t)b * kN * kC;
    const ushort* vbb = vB + ((size_t)b * kC + h * 32) * kN;

    const int arr   = wav >> 2;          // 0 = K (wav 0-3), 1 = V (wav 4-7)
    const int rbase = (wav & 3) * 16;    // 16 rows per wave

    // Q fragment: this wave's 16 rows (n = n0 + wav*16 + l16)
    bf16x8 qf[2];
#pragma unroll
    for (int kk = 0; kk < 2; ++kk) {
        int ng = n0 + wav * 16 + l16;
        qf[kk] = *(const bf16x8*)(qTb + (size_t)ng * kC + h * 32 + kk * 32 + quad * 8);
    }

    f32x4 oacc[4];
#pragma unroll
    for (int wt = 0; wt < 4; ++wt)
#pragma unroll
        for (int r = 0; r < 4; ++r) oacc[wt][r] = 0.f;
    float li = 0.f;   // per-lane partial; quad-aggregated at epilogue

    const int NIT = kN / 64;    // 32

    const int sa   = lane >> 3;           // dest sub-row within 8-row chunk
    const int sblk = (lane & 7) ^ sa;     // source block (swizzle on source)
    auto dmaTile = [&](int m0, int buf) {
#pragma unroll
        for (int p = 0; p < 2; ++p) {
            int rl = rbase + p * 8 + sa;
            const ushort* src = (arr == 0)
                ? (kTb + (size_t)(m0 + rl) * kC + h * 32 + sblk * 8)
                : (vbb + (size_t)rl * kN + m0 + sblk * 8);
            g2l16(src, &sKV[buf][arr * 4096 + (rbase + p * 8) * 64]);
        }
    };

    dmaTile(0, 0);
    __syncthreads();

    for (int it = 0; it < NIT; ++it) {
        const int cur = it & 1;
        const bool more = (it + 1 < NIT);
        if (more) dmaTile((it + 1) * 64, cur ^ 1);

        const ushort* sK = &sKV[cur][0];
        const ushort* sV = &sKV[cur][4096];

        // S^T[m][n] = sum_w K[w][m] Q[w][n]  (Q pre-scaled by log2e)
        f32x4 sacc[4];
#pragma unroll
        for (int mt = 0; mt < 4; ++mt)
#pragma unroll
            for (int r = 0; r < 4; ++r) sacc[mt][r] = 0.f;
        __builtin_amdgcn_s_setprio(1);
#pragma unroll
        for (int kk = 0; kk < 2; ++kk)
#pragma unroll
            for (int mt = 0; mt < 4; ++mt) {
                int row = mt * 16 + l16;
                bf16x8 af = *(const bf16x8*)&sK[row * 64 + (((kk * 4 + quad) ^ (row & 7)) * 8)];
                sacc[mt] = __builtin_amdgcn_mfma_f32_16x16x32_bf16(
                    af, qf[kk], sacc[mt], 0, 0, 0);
            }
        __builtin_amdgcn_s_setprio(0);

        // softmax numerators: p = exp2(S') directly; keep packed P in regs.
        unsigned d[4][2];
        {
            float sum = 0.f;
#pragma unroll
            for (int mt = 0; mt < 4; ++mt) {
                float p0 = fexp2(sacc[mt][0]);
                float p1 = fexp2(sacc[mt][1]);
                float p2 = fexp2(sacc[mt][2]);
                float p3 = fexp2(sacc[mt][3]);
                sum += (p0 + p1) + (p2 + p3);
                d[mt][0] = pk_bf16(p0, p1);
                d[mt][1] = pk_bf16(p2, p3);
            }
            li += sum;   // per-lane partial (this lane's m-slice)
        }

        // O[w][n] += sum_m V[w][m] P[m][n]; C->B regroup via permlane cascade
#pragma unroll
        for (int ks = 0; ks < 2; ++ks) {
            bf16x8 pf;
            {
                union { unsigned w[4]; bf16x8 v8; } pu;
#if __has_builtin(__builtin_amdgcn_permlane32_swap) && __has_builtin(__builtin_amdgcn_permlane16_swap)
#pragma unroll
                for (int rd = 0; rd < 2; ++rd) {
                    unsigned a = d[2 * ks][rd], bb = d[2 * ks + 1][rd];
                    auto r32 = __builtin_amdgcn_permlane32_swap(a, bb, false, false);
                    auto r16 = __builtin_amdgcn_permlane16_swap(r32[0], r32[1], false, false);
                    pu.w[rd]     = r16[0];
                    pu.w[2 + rd] = r16[1];
                }
#else
                const int gx = ((lane & 16) << 1) + l16;
                const int gy = gx + 16;
                const bool lo = (lane < 32);
#pragma unroll
                for (int rd = 0; rd < 2; ++rd) {
                    unsigned u = d[2 * ks][rd], v = d[2 * ks + 1][rd];
                    unsigned xu = (unsigned)__shfl((int)u, gx);
                    unsigned xv = (unsigned)__shfl((int)v, gx);
                    unsigned yu = (unsigned)__shfl((int)u, gy);
                    unsigned yv = (unsigned)__shfl((int)v, gy);
                    pu.w[rd]     = lo ? xu : xv;
                    pu.w[2 + rd] = lo ? yu : yv;
                }
#endif
                pf = pu.v8;
            }
            __builtin_amdgcn_s_setprio(1);
#pragma unroll
            for (int wt = 0; wt < 4; ++wt) {
                int wr = wt * 16 + l16;
                bf16x8 vf = *(const bf16x8*)&sV[wr * 64 + (((ks * 4 + quad) ^ (wr & 7)) * 8)];
                oacc[wt] = __builtin_amdgcn_mfma_f32_16x16x32_bf16(
                    vf, pf, oacc[wt], 0, 0, 0);
            }
            __builtin_amdgcn_s_setprio(0);
        }

        __syncthreads();   // drains DMA (vmcnt) + K/V LDS ops (lgkm)
    }

    // ---- epilogue: finish row-sum, normalize, LDS-transpose O, store ------
    li += __shfl_xor(li, 16);
    li += __shfl_xor(li, 32);
    float inv = 1.f / li;
    ushort* sT = &sKV[0][0];    // 128 rows x 64 ch x 2B = 16 KB (buf 0)
#pragma unroll
    for (int wt = 0; wt < 4; ++wt) {
        int nrow = wav * 16 + l16;   // 0..127
        int cb = (wt * 2 + (quad >> 1)) ^ (nrow & 7);
        *(ushort4*)&sT[nrow * 64 + cb * 8 + (quad & 1) * 4] =
            pack4bf(oacc[wt][0] * inv, oacc[wt][1] * inv,
                    oacc[wt][2] * inv, oacc[wt][3] * inv);
    }
    __syncthreads();
    int rsub = tid >> 3, blk = tid & 7;   // rsub 0..63
#pragma unroll
    for (int p = 0; p < 2; ++p) {
        int row = p * 64 + rsub;   // n_local 0..127
        int4 dd = *(const int4*)&sT[row * 64 + ((blk ^ (row & 7)) * 8)];
        *(int4*)&Opart[((size_t)b * kN + n0 + row) * kOC + h * 64 + blk * 8] = dd;
    }
}

// ---------------- final projection: pure DMA-GEMM (kSplit=1) ---------------
__global__ __launch_bounds__(256, 4) void proj_kernel(
    const ushort* __restrict__ Opart, const ushort* __restrict__ Wfb,
    const float* __restrict__ bf_, const float* __restrict__ sf,
    const float* __restrict__ bff, float* __restrict__ out)
{
    const int nt = blockIdx.x;   // 32 tiles of 64 n
    const int ot = blockIdx.y;   // 4 tiles of 64 o
    const int b  = blockIdx.z;
    __shared__ __align__(16) ushort sA[2][64 * 64];   // Wf tile   (16 KB)
    __shared__ __align__(16) ushort sB[2][64 * 64];   // Opart tile (16 KB)
    const int tid = threadIdx.x;
    const int lane = tid & 63, wav = tid >> 6;   // 4 waves
    const int quad = lane >> 4, l16 = lane & 15;

    const ushort* Wt = Wfb + (size_t)(ot * 64) * kOC;
    const ushort* Ob = Opart + ((size_t)b * kN + nt * 64) * kOC;

    f32x4 acc[4];
#pragma unroll
    for (int ntt = 0; ntt < 4; ++ntt)
#pragma unroll
        for (int r = 0; r < 4; ++r) acc[ntt][r] = 0.f;

    const int sa   = lane >> 3;           // dest sub-row within 8-row chunk
    const int sblk = (lane & 7) ^ sa;     // source block (swizzle on source)
    auto dmaT = [&](int kt, int buf) {
        int k0 = kt * 64;
#pragma unroll
        for (int p = 0; p < 2; ++p) {
            int row = wav * 16 + p * 8 + sa;
            int dbase = (wav * 16 + p * 8) * 64;
            g2l16(Wt + (size_t)row * kOC + k0 + sblk * 8, &sA[buf][dbase]);
            g2l16(Ob + (size_t)row * kOC + k0 + sblk * 8, &sB[buf][dbase]);
        }
    };

    dmaT(0, 0);
    __syncthreads();

    for (int kt = 0; kt < 7; ++kt) {
        const int cur = kt & 1;
        const bool more = (kt < 6);
        if (more) dmaT(kt + 1, cur ^ 1);
#pragma unroll
        for (int ks = 0; ks < 2; ++ks) {
            int arow = wav * 16 + l16;
            bf16x8 af = *(const bf16x8*)&sA[cur][arow * 64 + (((ks * 4 + quad) ^ (arow & 7)) * 8)];
#pragma unroll
            for (int ntt = 0; ntt < 4; ++ntt) {
                int brow = ntt * 16 + l16;
                bf16x8 bfr = *(const bf16x8*)&sB[cur][brow * 64 + (((ks * 4 + quad) ^ (brow & 7)) * 8)];
                acc[ntt] = __builtin_amdgcn_mfma_f32_16x16x32_bf16(af, bfr, acc[ntt], 0, 0, 0);
            }
        }
        __syncthreads();
    }
#pragma unroll
    for (int r = 0; r < 4; ++r) {
        int o = ot * 64 + wav * 16 + quad * 4 + r;
        float bfv = bf_[o], sfv = sf[o], bffv = bff[o];
#pragma unroll
        for (int ntt = 0; ntt < 4; ++ntt) {
            int n = nt * 64 + ntt * 16 + l16;
            float y = fmaf(acc[ntt][r] + bfv, sfv, bffv);
            out[((size_t)b * kC + o) * kN + n] = y > 0.f ? y : 0.f;
        }
    }
}

extern "C" void kernel_launch(void* const* d_in, const int* in_sizes, int n_in,
                              void* d_out, int out_size, void* d_ws, size_t ws_size,
                              hipStream_t stream) {
    const float* x   = (const float*)d_in[0];
    const float* Wq  = (const float*)d_in[1];
    const float* sq  = (const float*)d_in[2];
    const float* bq  = (const float*)d_in[3];
    const float* Wk  = (const float*)d_in[4];
    const float* sk  = (const float*)d_in[5];
    const float* bk  = (const float*)d_in[6];
    const float* Wv  = (const float*)d_in[7];
    const float* sv  = (const float*)d_in[8];
    const float* bv  = (const float*)d_in[9];
    const float* Wf  = (const float*)d_in[10];
    const float* bf_ = (const float*)d_in[11];
    const float* sf  = (const float*)d_in[12];
    const float* bff = (const float*)d_in[13];
    float* out = (float*)d_out;

    char* ws = (char*)d_ws;
    ushort* xT  = (ushort*)(ws);                         // 4,194,304
    ushort* Wqb = (ushort*)(ws + 4194304);               // 131,072
    ushort* Wkb = (ushort*)(ws + 4325376);               // 131,072
    ushort* Wvb = (ushort*)(ws + 4456448);               // 131,072
    ushort* Wfb = (ushort*)(ws + 4587520);               // 229,376
    ushort* qT  = (ushort*)(ws + 4816896);               // 4,194,304
    ushort* kT  = (ushort*)(ws + 9011200);               // 4,194,304
    ushort* vB  = (ushort*)(ws + 13205504);              // 4,194,304
    ushort* Opart = (ushort*)(ws + 17399808);            // 7,340,032 (single)

    prep_kernel<<<dim3(960), 256, 0, stream>>>(
        x, Wq, Wk, Wv, Wf, xT, Wqb, Wkb, Wvb, Wfb);
    qkv_kernel<<<dim3(384), 512, 0, stream>>>(
        xT, Wqb, Wkb, Wvb, sq, bq, sk, bk, sv, bv, qT, kT, vB);
    attn_kernel<<<dim3(448), 512, 0, stream>>>(
        qT, kT, vB, Opart);
    proj_kernel<<<dim3(kN / 64, kC / 64, kB), 256, 0, stream>>>(
        Opart, Wfb, bf_, sf, bff, out);
}